// Round 1
// baseline (5552.692 us; speedup 1.0000x reference)
//
#include <hip/hip_runtime.h>
#include <hip/hip_bf16.h>

#define NPTS 1000000
#define NSEG 50000
#define P1   32      // points per block (phase 1)
#define P2   32      // segments per block (phase 2)
#define LDP  36      // padded LDS row stride (keeps float4 alignment, spreads banks)

union F4 { float4 v; float f[4]; };

// ---------------- Phase 1: point MLP (11->64->128->256) + segment max ----------------
__global__ __launch_bounds__(256) void phase1(
    const float* __restrict__ x, const int* __restrict__ idx,
    const float* __restrict__ W0, const float* __restrict__ b0,
    const float* __restrict__ W1, const float* __restrict__ b1,
    const float* __restrict__ W2, const float* __restrict__ b2,
    unsigned int* __restrict__ g)
{
    __shared__ float xsT[11][LDP];    // x tile, transposed [chan][point]
    __shared__ float h1T[64][LDP];    // layer0 out, transposed
    __shared__ float h2T[128][LDP];   // layer1 out, transposed
    __shared__ int   seg[P1];

    const int t = threadIdx.x;
    const long base = (long)blockIdx.x * P1;

    // stage x tile (transposed) + segment ids
    for (int i = t; i < P1 * 11; i += 256) {
        int p = i / 11, c = i - p * 11;
        xsT[c][p] = x[(base + p) * 11 + c];
    }
    if (t < P1) seg[t] = idx[base + t];
    __syncthreads();

    const int p0 = (t & 7) << 2;   // 8 point-groups of 4
    const int jg = t >> 3;         // 32 channel-groups

    // ---- layer 0: 11 -> 64 (2 channels/thread) ----
    {
        const int j0 = jg << 1;
        float acc[2][4];
        #pragma unroll
        for (int jj = 0; jj < 2; ++jj) {
            float b = b0[j0 + jj];
            #pragma unroll
            for (int pp = 0; pp < 4; ++pp) acc[jj][pp] = b;
        }
        #pragma unroll
        for (int k = 0; k < 11; ++k) {
            F4 a; a.v = *(const float4*)&xsT[k][p0];
            float w0v = W0[k * 64 + j0];
            float w1v = W0[k * 64 + j0 + 1];
            #pragma unroll
            for (int pp = 0; pp < 4; ++pp) {
                acc[0][pp] = fmaf(a.f[pp], w0v, acc[0][pp]);
                acc[1][pp] = fmaf(a.f[pp], w1v, acc[1][pp]);
            }
        }
        #pragma unroll
        for (int jj = 0; jj < 2; ++jj) {
            F4 v;
            #pragma unroll
            for (int pp = 0; pp < 4; ++pp) v.f[pp] = fmaxf(acc[jj][pp], 0.f);
            *(float4*)&h1T[j0 + jj][p0] = v.v;
        }
    }
    __syncthreads();

    // ---- layer 1: 64 -> 128 (4 channels/thread) ----
    {
        const int j0 = jg << 2;
        float acc[4][4];
        #pragma unroll
        for (int jj = 0; jj < 4; ++jj) {
            float b = b1[j0 + jj];
            #pragma unroll
            for (int pp = 0; pp < 4; ++pp) acc[jj][pp] = b;
        }
        #pragma unroll 4
        for (int k = 0; k < 64; ++k) {
            F4 a; a.v = *(const float4*)&h1T[k][p0];
            F4 w; w.v = *(const float4*)&W1[k * 128 + j0];
            #pragma unroll
            for (int jj = 0; jj < 4; ++jj)
                #pragma unroll
                for (int pp = 0; pp < 4; ++pp)
                    acc[jj][pp] = fmaf(a.f[pp], w.f[jj], acc[jj][pp]);
        }
        #pragma unroll
        for (int jj = 0; jj < 4; ++jj) {
            F4 v;
            #pragma unroll
            for (int pp = 0; pp < 4; ++pp) v.f[pp] = fmaxf(acc[jj][pp], 0.f);
            *(float4*)&h2T[j0 + jj][p0] = v.v;
        }
    }
    __syncthreads();

    // ---- layer 2: 128 -> 256 (8 channels/thread) + relu + atomic segment-max ----
    {
        const int j0 = jg << 3;
        float acc[8][4];
        #pragma unroll
        for (int jj = 0; jj < 8; ++jj) {
            float b = b2[j0 + jj];
            #pragma unroll
            for (int pp = 0; pp < 4; ++pp) acc[jj][pp] = b;
        }
        #pragma unroll 4
        for (int k = 0; k < 128; ++k) {
            F4 a;  a.v  = *(const float4*)&h2T[k][p0];
            F4 wa; wa.v = *(const float4*)&W2[k * 256 + j0];
            F4 wb; wb.v = *(const float4*)&W2[k * 256 + j0 + 4];
            #pragma unroll
            for (int jj = 0; jj < 4; ++jj)
                #pragma unroll
                for (int pp = 0; pp < 4; ++pp) {
                    acc[jj][pp]     = fmaf(a.f[pp], wa.f[jj], acc[jj][pp]);
                    acc[jj + 4][pp] = fmaf(a.f[pp], wb.f[jj], acc[jj + 4][pp]);
                }
        }
        int s[4];
        #pragma unroll
        for (int pp = 0; pp < 4; ++pp) s[pp] = seg[p0 + pp];
        #pragma unroll
        for (int jj = 0; jj < 8; ++jj) {
            #pragma unroll
            for (int pp = 0; pp < 4; ++pp) {
                float v = fmaxf(acc[jj][pp], 0.f);   // >=0, so uint-max == float-max
                atomicMax(&g[(long)s[pp] * 256 + j0 + jj], __float_as_uint(v));
            }
        }
    }
}

// ---------------- Phase 2: segment MLP (256->256->128->13) ----------------
__global__ __launch_bounds__(256) void phase2(
    const float* __restrict__ g,
    const float* __restrict__ W3, const float* __restrict__ b3,
    const float* __restrict__ W4, const float* __restrict__ b4,
    const float* __restrict__ Wh, const float* __restrict__ bh,
    float* __restrict__ out)
{
    __shared__ float gT[256][LDP];    // segment features, transposed; reused as h5T
    __shared__ float h4T[256][LDP];   // layer3 out, transposed

    const int t = threadIdx.x;
    const long base = (long)blockIdx.x * P2;

    for (int i = t; i < P2 * 256; i += 256) {
        int s = i >> 8, c = i & 255;
        float v = 0.f;
        if (base + s < NSEG) v = g[(base + s) * 256 + c];
        gT[c][s] = v;
    }
    __syncthreads();

    const int p0 = (t & 7) << 2;
    const int jg = t >> 3;

    // ---- layer 3: 256 -> 256 ----
    {
        const int j0 = jg << 3;
        float acc[8][4];
        #pragma unroll
        for (int jj = 0; jj < 8; ++jj) {
            float b = b3[j0 + jj];
            #pragma unroll
            for (int pp = 0; pp < 4; ++pp) acc[jj][pp] = b;
        }
        #pragma unroll 4
        for (int k = 0; k < 256; ++k) {
            F4 a;  a.v  = *(const float4*)&gT[k][p0];
            F4 wa; wa.v = *(const float4*)&W3[k * 256 + j0];
            F4 wb; wb.v = *(const float4*)&W3[k * 256 + j0 + 4];
            #pragma unroll
            for (int jj = 0; jj < 4; ++jj)
                #pragma unroll
                for (int pp = 0; pp < 4; ++pp) {
                    acc[jj][pp]     = fmaf(a.f[pp], wa.f[jj], acc[jj][pp]);
                    acc[jj + 4][pp] = fmaf(a.f[pp], wb.f[jj], acc[jj + 4][pp]);
                }
        }
        __syncthreads();  // all gT reads done before anyone writes h4T? (different buffer; this sync is for gT reuse later)
        #pragma unroll
        for (int jj = 0; jj < 8; ++jj) {
            F4 v;
            #pragma unroll
            for (int pp = 0; pp < 4; ++pp) v.f[pp] = fmaxf(acc[jj][pp], 0.f);
            *(float4*)&h4T[j0 + jj][p0] = v.v;
        }
    }
    __syncthreads();

    // ---- layer 4: 256 -> 128 (writes into gT space as h5T) ----
    float (*h5T)[LDP] = gT;
    {
        const int j0 = jg << 2;
        float acc[4][4];
        #pragma unroll
        for (int jj = 0; jj < 4; ++jj) {
            float b = b4[j0 + jj];
            #pragma unroll
            for (int pp = 0; pp < 4; ++pp) acc[jj][pp] = b;
        }
        #pragma unroll 4
        for (int k = 0; k < 256; ++k) {
            F4 a; a.v = *(const float4*)&h4T[k][p0];
            F4 w; w.v = *(const float4*)&W4[k * 128 + j0];
            #pragma unroll
            for (int jj = 0; jj < 4; ++jj)
                #pragma unroll
                for (int pp = 0; pp < 4; ++pp)
                    acc[jj][pp] = fmaf(a.f[pp], w.f[jj], acc[jj][pp]);
        }
        #pragma unroll
        for (int jj = 0; jj < 4; ++jj) {
            F4 v;
            #pragma unroll
            for (int pp = 0; pp < 4; ++pp) v.f[pp] = fmaxf(acc[jj][pp], 0.f);
            *(float4*)&h5T[j0 + jj][p0] = v.v;
        }
    }
    __syncthreads();

    // ---- head: 128 -> 13 (no relu) ----
    {
        #pragma unroll
        for (int pass = 0; pass < 2; ++pass) {
            int p = (t >> 4) + pass * 16;
            int j = t & 15;
            if (j < 13 && base + p < NSEG) {
                float acc = bh[j];
                #pragma unroll 4
                for (int k = 0; k < 128; ++k)
                    acc = fmaf(h5T[k][p], Wh[k * 13 + j], acc);
                out[(base + p) * 13 + j] = acc;
            }
        }
    }
}

extern "C" void kernel_launch(void* const* d_in, const int* in_sizes, int n_in,
                              void* d_out, int out_size, void* d_ws, size_t ws_size,
                              hipStream_t stream)
{
    const float* x  = (const float*)d_in[0];
    const int*   idx= (const int*)  d_in[1];
    const float* W0 = (const float*)d_in[2];
    const float* b0 = (const float*)d_in[3];
    const float* W1 = (const float*)d_in[4];
    const float* b1 = (const float*)d_in[5];
    const float* W2 = (const float*)d_in[6];
    const float* b2 = (const float*)d_in[7];
    const float* W3 = (const float*)d_in[8];
    const float* b3 = (const float*)d_in[9];
    const float* W4 = (const float*)d_in[10];
    const float* b4 = (const float*)d_in[11];
    const float* Wh = (const float*)d_in[12];
    const float* bh = (const float*)d_in[13];
    float* out = (float*)d_out;

    unsigned int* g = (unsigned int*)d_ws;   // [NSEG][256] fp32 bit patterns, all >= 0

    // zero-init g: implements both the max identity (values are post-ReLU >= 0)
    // and the reference's empty-segment -> 0 rule.
    hipMemsetAsync(d_ws, 0, (size_t)NSEG * 256 * sizeof(float), stream);

    phase1<<<NPTS / P1, 256, 0, stream>>>(x, idx, W0, b0, W1, b1, W2, b2, g);
    phase2<<<(NSEG + P2 - 1) / P2, 256, 0, stream>>>((const float*)g, W3, b3, W4, b4, Wh, bh, out);
}

// Round 4
// 1995.600 us; speedup vs baseline: 2.7825x; 2.7825x over previous
//
#include <hip/hip_runtime.h>
#include <hip/hip_bf16.h>

#define NPTS 1000000
#define NSEG 50000
#define SPB  8       // segments per block (phase 1)
#define P2   32      // segments per block (phase 2)
#define LDP  36      // padded LDS row stride

union F4 { float4 v; float f[4]; };

// ---------- sort machinery: histogram -> scan -> scatter ----------
__global__ __launch_bounds__(256) void hist_kernel(const int* __restrict__ idx,
                                                   unsigned* __restrict__ counts) {
    int i = blockIdx.x * blockDim.x + threadIdx.x;
    for (; i < NPTS; i += gridDim.x * blockDim.x) atomicAdd(&counts[idx[i]], 1u);
}

// exclusive-scan counts -> start[50000]; after scatter, start[s] becomes end-of-s.
__global__ __launch_bounds__(1024) void scan_kernel(const unsigned* __restrict__ counts,
                                                    unsigned* __restrict__ start) {
    __shared__ unsigned tmp[1024];
    __shared__ unsigned carry;
    const int t = threadIdx.x;
    if (t == 0) carry = 0;
    __syncthreads();
    for (int base = 0; base < NSEG; base += 1024) {
        unsigned v = (base + t < NSEG) ? counts[base + t] : 0u;
        tmp[t] = v;
        __syncthreads();
        for (int off = 1; off < 1024; off <<= 1) {
            unsigned add = (t >= off) ? tmp[t - off] : 0u;
            __syncthreads();
            tmp[t] += add;
            __syncthreads();
        }
        if (base + t < NSEG) start[base + t] = carry + tmp[t] - v;  // exclusive
        __syncthreads();
        if (t == 0) carry += tmp[1023];
        __syncthreads();
    }
}

// scatter point ids into segment-sorted order; start[s] advances to end-of-s.
__global__ __launch_bounds__(256) void scatter_kernel(const int* __restrict__ idx,
                                                      unsigned* __restrict__ start,
                                                      unsigned* __restrict__ perm) {
    int i = blockIdx.x * blockDim.x + threadIdx.x;
    for (; i < NPTS; i += gridDim.x * blockDim.x) {
        int s = idx[i];
        unsigned pos = atomicAdd(&start[s], 1u);
        perm[pos] = (unsigned)i;
    }
}

// ---------- Phase 1: point MLP + segment max (block owns 8 segments) ----------
// After scatter, start[s] == end offset of segment s (== original start[s+1]).
__global__ __launch_bounds__(256) void phase1s(
    const float* __restrict__ x, const int* __restrict__ idx,
    const unsigned* __restrict__ endofs, const unsigned* __restrict__ perm,
    const float* __restrict__ W0, const float* __restrict__ b0,
    const float* __restrict__ W1, const float* __restrict__ b1,
    const float* __restrict__ W2, const float* __restrict__ b2,
    float* __restrict__ g)
{
    __shared__ float xsT[11][LDP];           // x chunk, transposed
    __shared__ float h1T[64][LDP];
    __shared__ float h2T[128][LDP];
    __shared__ unsigned gmax[SPB + 1][264];  // row 8 = dummy for padded lanes
    __shared__ unsigned pi_s[32];
    __shared__ int      segl_s[32];

    const int t  = threadIdx.x;
    const int s0 = blockIdx.x * SPB;
    const unsigned A = (s0 == 0) ? 0u : endofs[s0 - 1];
    const unsigned B = endofs[s0 + SPB - 1];

    for (int i = t; i < (SPB + 1) * 264; i += 256) ((unsigned*)gmax)[i] = 0u;

    const int p0 = (t & 7) << 2;   // 8 point-groups of 4
    const int jg = t >> 3;         // 32 channel-groups

    const int nchunk = (int)(B - A + 31u) >> 5;
    for (int c = 0; c < nchunk; ++c) {
        // stage point ids + local segment ids for this 32-point chunk
        if (t < 32) {
            unsigned gp = A + ((unsigned)c << 5) + (unsigned)t;
            if (gp < B) {
                unsigned p = perm[gp];
                pi_s[t]   = p;
                segl_s[t] = idx[p] - s0;
            } else {
                pi_s[t]   = 0xFFFFFFFFu;
                segl_s[t] = SPB;          // dummy row
            }
        }
        __syncthreads();
        for (int i = t; i < 32 * 11; i += 256) {
            int p = i / 11, ch = i - p * 11;
            unsigned pid = pi_s[p];
            xsT[ch][p] = (pid != 0xFFFFFFFFu) ? x[(long)pid * 11 + ch] : 0.f;
        }
        __syncthreads();

        // ---- layer 0: 11 -> 64 (2 ch/thread) ----
        {
            const int j0 = jg << 1;
            float acc[2][4];
            #pragma unroll
            for (int jj = 0; jj < 2; ++jj) {
                float b = b0[j0 + jj];
                #pragma unroll
                for (int pp = 0; pp < 4; ++pp) acc[jj][pp] = b;
            }
            #pragma unroll
            for (int k = 0; k < 11; ++k) {
                F4 a; a.v = *(const float4*)&xsT[k][p0];
                float w0v = W0[k * 64 + j0];
                float w1v = W0[k * 64 + j0 + 1];
                #pragma unroll
                for (int pp = 0; pp < 4; ++pp) {
                    acc[0][pp] = fmaf(a.f[pp], w0v, acc[0][pp]);
                    acc[1][pp] = fmaf(a.f[pp], w1v, acc[1][pp]);
                }
            }
            #pragma unroll
            for (int jj = 0; jj < 2; ++jj) {
                F4 v;
                #pragma unroll
                for (int pp = 0; pp < 4; ++pp) v.f[pp] = fmaxf(acc[jj][pp], 0.f);
                *(float4*)&h1T[j0 + jj][p0] = v.v;
            }
        }
        __syncthreads();

        // ---- layer 1: 64 -> 128 (4 ch/thread) ----
        {
            const int j0 = jg << 2;
            float acc[4][4];
            #pragma unroll
            for (int jj = 0; jj < 4; ++jj) {
                float b = b1[j0 + jj];
                #pragma unroll
                for (int pp = 0; pp < 4; ++pp) acc[jj][pp] = b;
            }
            #pragma unroll 4
            for (int k = 0; k < 64; ++k) {
                F4 a; a.v = *(const float4*)&h1T[k][p0];
                F4 w; w.v = *(const float4*)&W1[k * 128 + j0];
                #pragma unroll
                for (int jj = 0; jj < 4; ++jj)
                    #pragma unroll
                    for (int pp = 0; pp < 4; ++pp)
                        acc[jj][pp] = fmaf(a.f[pp], w.f[jj], acc[jj][pp]);
            }
            #pragma unroll
            for (int jj = 0; jj < 4; ++jj) {
                F4 v;
                #pragma unroll
                for (int pp = 0; pp < 4; ++pp) v.f[pp] = fmaxf(acc[jj][pp], 0.f);
                *(float4*)&h2T[j0 + jj][p0] = v.v;
            }
        }
        __syncthreads();

        // ---- layer 2: 128 -> 256 (8 ch/thread) + relu + LDS segment max ----
        {
            const int j0 = jg << 3;
            float acc[8][4];
            #pragma unroll
            for (int jj = 0; jj < 8; ++jj) {
                float b = b2[j0 + jj];
                #pragma unroll
                for (int pp = 0; pp < 4; ++pp) acc[jj][pp] = b;
            }
            #pragma unroll 4
            for (int k = 0; k < 128; ++k) {
                F4 a;  a.v  = *(const float4*)&h2T[k][p0];
                F4 wa; wa.v = *(const float4*)&W2[k * 256 + j0];
                F4 wb; wb.v = *(const float4*)&W2[k * 256 + j0 + 4];
                #pragma unroll
                for (int jj = 0; jj < 4; ++jj)
                    #pragma unroll
                    for (int pp = 0; pp < 4; ++pp) {
                        acc[jj][pp]     = fmaf(a.f[pp], wa.f[jj], acc[jj][pp]);
                        acc[jj + 4][pp] = fmaf(a.f[pp], wb.f[jj], acc[jj + 4][pp]);
                    }
            }
            int s[4];
            #pragma unroll
            for (int pp = 0; pp < 4; ++pp) s[pp] = segl_s[p0 + pp];
            #pragma unroll
            for (int jj = 0; jj < 8; ++jj) {
                #pragma unroll
                for (int pp = 0; pp < 4; ++pp) {
                    float v = fmaxf(acc[jj][pp], 0.f);      // >=0: uint max == float max
                    atomicMax(&gmax[s[pp]][j0 + jj], __float_as_uint(v));
                }
            }
        }
        __syncthreads();   // atomics done; safe to overwrite pi_s/xsT next chunk
    }
    __syncthreads();       // covers nchunk==0 (gmax init visibility)

    // write the 8x256 segment tile (already >=0; empty segments = 0)
    for (int i = t; i < SPB * 256; i += 256) {
        int sl = i >> 8, ch = i & 255;
        g[(long)(s0 + sl) * 256 + ch] = __uint_as_float(gmax[sl][ch]);
    }
}

// ---------------- Phase 2: segment MLP (256->256->128->13) ----------------
__global__ __launch_bounds__(256) void phase2(
    const float* __restrict__ g,
    const float* __restrict__ W3, const float* __restrict__ b3,
    const float* __restrict__ W4, const float* __restrict__ b4,
    const float* __restrict__ Wh, const float* __restrict__ bh,
    float* __restrict__ out)
{
    __shared__ float gT[256][LDP];    // reused as h5T
    __shared__ float h4T[256][LDP];

    const int t = threadIdx.x;
    const long base = (long)blockIdx.x * P2;

    for (int i = t; i < P2 * 256; i += 256) {
        int s = i >> 8, c = i & 255;
        float v = 0.f;
        if (base + s < NSEG) v = g[(base + s) * 256 + c];
        gT[c][s] = v;
    }
    __syncthreads();

    const int p0 = (t & 7) << 2;
    const int jg = t >> 3;

    // ---- layer 3: 256 -> 256 ----
    {
        const int j0 = jg << 3;
        float acc[8][4];
        #pragma unroll
        for (int jj = 0; jj < 8; ++jj) {
            float b = b3[j0 + jj];
            #pragma unroll
            for (int pp = 0; pp < 4; ++pp) acc[jj][pp] = b;
        }
        #pragma unroll 4
        for (int k = 0; k < 256; ++k) {
            F4 a;  a.v  = *(const float4*)&gT[k][p0];
            F4 wa; wa.v = *(const float4*)&W3[k * 256 + j0];
            F4 wb; wb.v = *(const float4*)&W3[k * 256 + j0 + 4];
            #pragma unroll
            for (int jj = 0; jj < 4; ++jj)
                #pragma unroll
                for (int pp = 0; pp < 4; ++pp) {
                    acc[jj][pp]     = fmaf(a.f[pp], wa.f[jj], acc[jj][pp]);
                    acc[jj + 4][pp] = fmaf(a.f[pp], wb.f[jj], acc[jj + 4][pp]);
                }
        }
        __syncthreads();
        #pragma unroll
        for (int jj = 0; jj < 8; ++jj) {
            F4 v;
            #pragma unroll
            for (int pp = 0; pp < 4; ++pp) v.f[pp] = fmaxf(acc[jj][pp], 0.f);
            *(float4*)&h4T[j0 + jj][p0] = v.v;
        }
    }
    __syncthreads();

    // ---- layer 4: 256 -> 128 (into gT as h5T) ----
    float (*h5T)[LDP] = gT;
    {
        const int j0 = jg << 2;
        float acc[4][4];
        #pragma unroll
        for (int jj = 0; jj < 4; ++jj) {
            float b = b4[j0 + jj];
            #pragma unroll
            for (int pp = 0; pp < 4; ++pp) acc[jj][pp] = b;
        }
        #pragma unroll 4
        for (int k = 0; k < 256; ++k) {
            F4 a; a.v = *(const float4*)&h4T[k][p0];
            F4 w; w.v = *(const float4*)&W4[k * 128 + j0];
            #pragma unroll
            for (int jj = 0; jj < 4; ++jj)
                #pragma unroll
                for (int pp = 0; pp < 4; ++pp)
                    acc[jj][pp] = fmaf(a.f[pp], w.f[jj], acc[jj][pp]);
        }
        #pragma unroll
        for (int jj = 0; jj < 4; ++jj) {
            F4 v;
            #pragma unroll
            for (int pp = 0; pp < 4; ++pp) v.f[pp] = fmaxf(acc[jj][pp], 0.f);
            *(float4*)&h5T[j0 + jj][p0] = v.v;
        }
    }
    __syncthreads();

    // ---- head: 128 -> 13 ----
    {
        #pragma unroll
        for (int pass = 0; pass < 2; ++pass) {
            int p = (t >> 4) + pass * 16;
            int j = t & 15;
            if (j < 13 && base + p < NSEG) {
                float acc = bh[j];
                #pragma unroll 4
                for (int k = 0; k < 128; ++k)
                    acc = fmaf(h5T[k][p], Wh[k * 13 + j], acc);
                out[(base + p) * 13 + j] = acc;
            }
        }
    }
}

extern "C" void kernel_launch(void* const* d_in, const int* in_sizes, int n_in,
                              void* d_out, int out_size, void* d_ws, size_t ws_size,
                              hipStream_t stream)
{
    const float* x  = (const float*)d_in[0];
    const int*   idx= (const int*)  d_in[1];
    const float* W0 = (const float*)d_in[2];
    const float* b0 = (const float*)d_in[3];
    const float* W1 = (const float*)d_in[4];
    const float* b1 = (const float*)d_in[5];
    const float* W2 = (const float*)d_in[6];
    const float* b2 = (const float*)d_in[7];
    const float* W3 = (const float*)d_in[8];
    const float* b3 = (const float*)d_in[9];
    const float* W4 = (const float*)d_in[10];
    const float* b4 = (const float*)d_in[11];
    const float* Wh = (const float*)d_in[12];
    const float* bh = (const float*)d_in[13];
    float* out = (float*)d_out;

    // workspace layout (u32 units): counts[50048] | start[50048] | perm[1000000] | g
    unsigned* counts = (unsigned*)d_ws;
    unsigned* start  = counts + 50048;
    unsigned* perm   = start + 50048;
    float*    g      = (float*)(perm + 1000000);   // 50000*256 floats

    hipMemsetAsync(counts, 0, NSEG * sizeof(unsigned), stream);
    hist_kernel   <<<1024, 256, 0, stream>>>(idx, counts);
    scan_kernel   <<<1, 1024, 0, stream>>>(counts, start);
    scatter_kernel<<<1024, 256, 0, stream>>>(idx, start, perm);   // start[s] -> end-of-s
    phase1s       <<<NSEG / SPB, 256, 0, stream>>>(x, idx, start, perm,
                                                   W0, b0, W1, b1, W2, b2, g);
    phase2        <<<(NSEG + P2 - 1) / P2, 256, 0, stream>>>(g, W3, b3, W4, b4, Wh, bh, out);
}

// Round 5
// 882.348 us; speedup vs baseline: 6.2931x; 2.2617x over previous
//
#include <hip/hip_runtime.h>
#include <hip/hip_bf16.h>

#define NPTS 1000000
#define NSEG 50000
#define SPB  8       // segments per block (phase 1)
#define P2   32      // segments per block (phase 2)
#define LDP  36      // padded LDS row stride (phase 2 / xsT)

typedef __attribute__((ext_vector_type(8))) short bf16x8;   // 8 bf16 = 4 VGPR (MFMA A/B)
typedef __attribute__((ext_vector_type(4))) float f32x4;    // MFMA C/D

union F4 { float4 v; float f[4]; };

__device__ __forceinline__ unsigned short f2bf(float f) {
    union { __hip_bfloat16 h; unsigned short u; } cv;
    cv.h = __float2bfloat16(f);
    return cv.u;
}
__device__ __forceinline__ float bf2f(unsigned short u) {
    union { unsigned short u; __hip_bfloat16 h; } cv;
    cv.u = u;
    return __bfloat162float(cv.h);
}

#define MFMA16(a, b, c) __builtin_amdgcn_mfma_f32_16x16x32_bf16(a, b, c, 0, 0, 0)

// ---------- sort machinery: histogram -> scan -> scatter ----------
__global__ __launch_bounds__(256) void hist_kernel(const int* __restrict__ idx,
                                                   unsigned* __restrict__ counts) {
    int i = blockIdx.x * blockDim.x + threadIdx.x;
    for (; i < NPTS; i += gridDim.x * blockDim.x) atomicAdd(&counts[idx[i]], 1u);
}

__global__ __launch_bounds__(1024) void scan_kernel(const unsigned* __restrict__ counts,
                                                    unsigned* __restrict__ start) {
    __shared__ unsigned tmp[1024];
    __shared__ unsigned carry;
    const int t = threadIdx.x;
    if (t == 0) carry = 0;
    __syncthreads();
    for (int base = 0; base < NSEG; base += 1024) {
        unsigned v = (base + t < NSEG) ? counts[base + t] : 0u;
        tmp[t] = v;
        __syncthreads();
        for (int off = 1; off < 1024; off <<= 1) {
            unsigned add = (t >= off) ? tmp[t - off] : 0u;
            __syncthreads();
            tmp[t] += add;
            __syncthreads();
        }
        if (base + t < NSEG) start[base + t] = carry + tmp[t] - v;  // exclusive
        __syncthreads();
        if (t == 0) carry += tmp[1023];
        __syncthreads();
    }
}

__global__ __launch_bounds__(256) void scatter_kernel(const int* __restrict__ idx,
                                                      unsigned* __restrict__ start,
                                                      unsigned* __restrict__ perm) {
    int i = blockIdx.x * blockDim.x + threadIdx.x;
    for (; i < NPTS; i += gridDim.x * blockDim.x) {
        int s = idx[i];
        unsigned pos = atomicAdd(&start[s], 1u);
        perm[pos] = (unsigned)i;
    }
}

// ---------- weight packing: W1/W2 -> bf16 MFMA B-fragment order ----------
// Wpack1: [8 nt][2 kt][64 lane][8 e], Wpack2 at +8192: [16 nt][4 kt][64][8]
// B-frag (16x16x32): lane l holds B[k = kt*32 + (l>>4)*8 + e][n = nt*16 + (l&15)]
__global__ __launch_bounds__(256) void pack_weights(const float* __restrict__ W1,
                                                    const float* __restrict__ W2,
                                                    unsigned short* __restrict__ wp) {
    int i = blockIdx.x * 256 + threadIdx.x;
    const int total = 8192 + 32768;
    for (; i < total; i += gridDim.x * 256) {
        if (i < 8192) {
            int e = i & 7, l = (i >> 3) & 63, kt = (i >> 9) & 1, nt = i >> 10;
            int k = kt * 32 + (l >> 4) * 8 + e, n = nt * 16 + (l & 15);
            wp[i] = f2bf(W1[k * 128 + n]);
        } else {
            int j = i - 8192;
            int e = j & 7, l = (j >> 3) & 63, kt = (j >> 9) & 3, nt = j >> 11;
            int k = kt * 32 + (l >> 4) * 8 + e, n = nt * 16 + (l & 15);
            wp[i] = f2bf(W2[k * 256 + n]);
        }
    }
}

// ---------- Phase 1: point MLP (MFMA L1/L2) + segment max ----------
// L0 fp32 VALU (K=11), L1/L2 via 16x16x32 bf16 MFMA, activations split hi/lo bf16.
__global__ __launch_bounds__(256) void phase1m(
    const float* __restrict__ x, const int* __restrict__ idx,
    const unsigned* __restrict__ endofs, const unsigned* __restrict__ perm,
    const float* __restrict__ W0, const float* __restrict__ b0,
    const unsigned short* __restrict__ wp,    // packed W1 (+W2 at +8192)
    const float* __restrict__ b1, const float* __restrict__ b2,
    float* __restrict__ g)
{
    // activation planes, point-major, padded (72/136 ushort rows = 9/17 16B-units)
    __shared__ __align__(16) unsigned short h1hi[32 * 72];
    __shared__ __align__(16) unsigned short h1lo[32 * 72];
    __shared__ __align__(16) unsigned short h2hi[32 * 136];
    __shared__ __align__(16) unsigned short h2lo[32 * 136];
    __shared__ float xsT[11][LDP];
    __shared__ float w0s[11 * 64];
    __shared__ unsigned gmax[SPB][264];
    __shared__ int segl[32];

    const int t    = threadIdx.x;
    const int lane = t & 63;
    const int w    = t >> 6;          // wave 0..3
    const int col  = lane & 15;       // MFMA col (N) / A-row (M)
    const int grp  = lane >> 4;       // MFMA k-group / row-group
    const int s0   = blockIdx.x * SPB;

    const unsigned A = (s0 == 0) ? 0u : endofs[s0 - 1];
    const unsigned B = endofs[s0 + SPB - 1];

    // per-wave tile assignment: each wave = both M-tiles x a quarter of N
    const int nt2 = w * 2;   // L1: nts {nt2, nt2+1} of 8
    const int nt4 = w * 4;   // L2: nts {nt4..nt4+3} of 16

    // hoist weights/biases into registers (fixed per lane for the whole kernel)
    bf16x8 w1f[2][2], w2f[4][4];
    #pragma unroll
    for (int n = 0; n < 2; ++n)
        #pragma unroll
        for (int kt = 0; kt < 2; ++kt)
            w1f[n][kt] = *(const bf16x8*)&wp[(((nt2 + n) * 2 + kt) * 64 + lane) * 8];
    #pragma unroll
    for (int n = 0; n < 4; ++n)
        #pragma unroll
        for (int kt = 0; kt < 4; ++kt)
            w2f[n][kt] = *(const bf16x8*)&wp[8192 + (((nt4 + n) * 4 + kt) * 64 + lane) * 8];
    float bias1[2], bias2[4];
    #pragma unroll
    for (int n = 0; n < 2; ++n) bias1[n] = b1[(nt2 + n) * 16 + col];
    #pragma unroll
    for (int n = 0; n < 4; ++n) bias2[n] = b2[(nt4 + n) * 16 + col];

    // L0 mapping (fp32 VALU): 8 point-groups x 32 channel-pairs
    const int p0 = (t & 7) << 2;
    const int j0 = (t >> 3) << 1;
    float bias0a = b0[j0], bias0b = b0[j0 + 1];

    // init gmax + stage W0
    for (int i = t; i < SPB * 264; i += 256) ((unsigned*)gmax)[i] = 0u;
    for (int i = t; i < 11 * 64; i += 256) w0s[i] = W0[i];
    __syncthreads();

    const int nchunk = (int)(B - A + 31u) >> 5;
    for (int c = 0; c < nchunk; ++c) {
        // ---- stage: segment ids + x chunk (transposed) ----
        if (t < 32) {
            unsigned gp = A + ((unsigned)c << 5) + (unsigned)t;
            segl[t] = (gp < B) ? (idx[perm[gp]] - s0) : -1;
        }
        for (int i = t; i < 32 * 11; i += 256) {
            int p = i / 11, ch = i - p * 11;
            unsigned gp = A + ((unsigned)c << 5) + (unsigned)p;
            float v = 0.f;
            if (gp < B) v = x[perm[gp] * 11 + ch];
            xsT[ch][p] = v;
        }
        __syncthreads();

        // ---- L0: 11 -> 64, fp32, write split-bf16 point-major ----
        {
            float acc0[2][4];
            #pragma unroll
            for (int pp = 0; pp < 4; ++pp) { acc0[0][pp] = bias0a; acc0[1][pp] = bias0b; }
            #pragma unroll
            for (int k = 0; k < 11; ++k) {
                F4 a; a.v = *(const float4*)&xsT[k][p0];
                float wv0 = w0s[k * 64 + j0];
                float wv1 = w0s[k * 64 + j0 + 1];
                #pragma unroll
                for (int pp = 0; pp < 4; ++pp) {
                    acc0[0][pp] = fmaf(a.f[pp], wv0, acc0[0][pp]);
                    acc0[1][pp] = fmaf(a.f[pp], wv1, acc0[1][pp]);
                }
            }
            #pragma unroll
            for (int pp = 0; pp < 4; ++pp) {
                int pt = p0 + pp;
                float v0 = fmaxf(acc0[0][pp], 0.f);
                float v1 = fmaxf(acc0[1][pp], 0.f);
                unsigned short h0 = f2bf(v0), h1v = f2bf(v1);
                unsigned short l0 = f2bf(v0 - bf2f(h0)), l1v = f2bf(v1 - bf2f(h1v));
                *(unsigned*)&h1hi[pt * 72 + j0] = (unsigned)h0 | ((unsigned)h1v << 16);
                *(unsigned*)&h1lo[pt * 72 + j0] = (unsigned)l0 | ((unsigned)l1v << 16);
            }
        }
        __syncthreads();

        // ---- L1: 64 -> 128 MFMA (A split hi/lo) ----
        {
            f32x4 acc[2][2];
            #pragma unroll
            for (int m = 0; m < 2; ++m)
                #pragma unroll
                for (int n = 0; n < 2; ++n) {
                    float b = bias1[n];
                    acc[m][n] = (f32x4){b, b, b, b};
                }
            #pragma unroll
            for (int kt = 0; kt < 2; ++kt) {
                bf16x8 ahi[2], alo[2];
                #pragma unroll
                for (int m = 0; m < 2; ++m) {
                    int off = (m * 16 + col) * 72 + kt * 32 + grp * 8;
                    ahi[m] = *(const bf16x8*)&h1hi[off];
                    alo[m] = *(const bf16x8*)&h1lo[off];
                }
                #pragma unroll
                for (int n = 0; n < 2; ++n)
                    #pragma unroll
                    for (int m = 0; m < 2; ++m) {
                        acc[m][n] = MFMA16(ahi[m], w1f[n][kt], acc[m][n]);
                        acc[m][n] = MFMA16(alo[m], w1f[n][kt], acc[m][n]);
                    }
            }
            // write h2 (relu, split) — C/D map: row = grp*4 + r, col = lane&15
            #pragma unroll
            for (int m = 0; m < 2; ++m)
                #pragma unroll
                for (int n = 0; n < 2; ++n) {
                    int ch = (nt2 + n) * 16 + col;
                    #pragma unroll
                    for (int r = 0; r < 4; ++r) {
                        int pt = m * 16 + grp * 4 + r;
                        float v = fmaxf(acc[m][n][r], 0.f);
                        unsigned short hi = f2bf(v);
                        h2hi[pt * 136 + ch] = hi;
                        h2lo[pt * 136 + ch] = f2bf(v - bf2f(hi));
                    }
                }
        }
        __syncthreads();

        // ---- L2: 128 -> 256 MFMA + relu + LDS segment max ----
        {
            f32x4 acc2[2][4];
            #pragma unroll
            for (int m = 0; m < 2; ++m)
                #pragma unroll
                for (int n = 0; n < 4; ++n) {
                    float b = bias2[n];
                    acc2[m][n] = (f32x4){b, b, b, b};
                }
            #pragma unroll
            for (int kt = 0; kt < 4; ++kt) {
                bf16x8 ahi[2], alo[2];
                #pragma unroll
                for (int m = 0; m < 2; ++m) {
                    int off = (m * 16 + col) * 136 + kt * 32 + grp * 8;
                    ahi[m] = *(const bf16x8*)&h2hi[off];
                    alo[m] = *(const bf16x8*)&h2lo[off];
                }
                #pragma unroll
                for (int n = 0; n < 4; ++n)
                    #pragma unroll
                    for (int m = 0; m < 2; ++m) {
                        acc2[m][n] = MFMA16(ahi[m], w2f[n][kt], acc2[m][n]);
                        acc2[m][n] = MFMA16(alo[m], w2f[n][kt], acc2[m][n]);
                    }
            }
            // epilogue: relu + run-compressed LDS atomicMax (points sorted by segment)
            int slv[2][4];
            #pragma unroll
            for (int m = 0; m < 2; ++m)
                #pragma unroll
                for (int r = 0; r < 4; ++r)
                    slv[m][r] = segl[m * 16 + grp * 4 + r];
            #pragma unroll
            for (int m = 0; m < 2; ++m) {
                if (slv[m][0] < 0) continue;     // sorted: first invalid => all invalid
                #pragma unroll
                for (int n = 0; n < 4; ++n) {
                    int ch = (nt4 + n) * 16 + col;
                    float v0 = fmaxf(acc2[m][n][0], 0.f);
                    float v1 = fmaxf(acc2[m][n][1], 0.f);
                    float v2 = fmaxf(acc2[m][n][2], 0.f);
                    float v3 = fmaxf(acc2[m][n][3], 0.f);
                    if (slv[m][0] == slv[m][3]) {
                        float mx = fmaxf(fmaxf(v0, v1), fmaxf(v2, v3));
                        atomicMax(&gmax[slv[m][0]][ch], __float_as_uint(mx));
                    } else {
                        atomicMax(&gmax[slv[m][0]][ch], __float_as_uint(v0));
                        if (slv[m][1] >= 0) atomicMax(&gmax[slv[m][1]][ch], __float_as_uint(v1));
                        if (slv[m][2] >= 0) atomicMax(&gmax[slv[m][2]][ch], __float_as_uint(v2));
                        if (slv[m][3] >= 0) atomicMax(&gmax[slv[m][3]][ch], __float_as_uint(v3));
                    }
                }
            }
        }
        __syncthreads();
    }

    // write the 8x256 segment tile (>=0; empty segments = 0)
    for (int i = t; i < SPB * 256; i += 256) {
        int sl = i >> 8, ch = i & 255;
        g[(s0 + sl) * 256 + ch] = __uint_as_float(gmax[sl][ch]);
    }
}

// ---------------- Phase 2: segment MLP (256->256->128->13), fp32 ----------------
__global__ __launch_bounds__(256) void phase2(
    const float* __restrict__ g,
    const float* __restrict__ W3, const float* __restrict__ b3,
    const float* __restrict__ W4, const float* __restrict__ b4,
    const float* __restrict__ Wh, const float* __restrict__ bh,
    float* __restrict__ out)
{
    __shared__ float gT[256][LDP];    // reused as h5T
    __shared__ float h4T[256][LDP];

    const int t = threadIdx.x;
    const long base = (long)blockIdx.x * P2;

    for (int i = t; i < P2 * 256; i += 256) {
        int s = i >> 8, c = i & 255;
        float v = 0.f;
        if (base + s < NSEG) v = g[(base + s) * 256 + c];
        gT[c][s] = v;
    }
    __syncthreads();

    const int p0 = (t & 7) << 2;
    const int jg = t >> 3;

    // ---- layer 3: 256 -> 256 ----
    {
        const int j0 = jg << 3;
        float acc[8][4];
        #pragma unroll
        for (int jj = 0; jj < 8; ++jj) {
            float b = b3[j0 + jj];
            #pragma unroll
            for (int pp = 0; pp < 4; ++pp) acc[jj][pp] = b;
        }
        #pragma unroll 4
        for (int k = 0; k < 256; ++k) {
            F4 a;  a.v  = *(const float4*)&gT[k][p0];
            F4 wa; wa.v = *(const float4*)&W3[k * 256 + j0];
            F4 wb; wb.v = *(const float4*)&W3[k * 256 + j0 + 4];
            #pragma unroll
            for (int jj = 0; jj < 4; ++jj)
                #pragma unroll
                for (int pp = 0; pp < 4; ++pp) {
                    acc[jj][pp]     = fmaf(a.f[pp], wa.f[jj], acc[jj][pp]);
                    acc[jj + 4][pp] = fmaf(a.f[pp], wb.f[jj], acc[jj + 4][pp]);
                }
        }
        __syncthreads();
        #pragma unroll
        for (int jj = 0; jj < 8; ++jj) {
            F4 v;
            #pragma unroll
            for (int pp = 0; pp < 4; ++pp) v.f[pp] = fmaxf(acc[jj][pp], 0.f);
            *(float4*)&h4T[j0 + jj][p0] = v.v;
        }
    }
    __syncthreads();

    // ---- layer 4: 256 -> 128 (into gT as h5T) ----
    float (*h5T)[LDP] = gT;
    {
        const int j0 = jg << 2;
        float acc[4][4];
        #pragma unroll
        for (int jj = 0; jj < 4; ++jj) {
            float b = b4[j0 + jj];
            #pragma unroll
            for (int pp = 0; pp < 4; ++pp) acc[jj][pp] = b;
        }
        #pragma unroll 4
        for (int k = 0; k < 256; ++k) {
            F4 a; a.v = *(const float4*)&h4T[k][p0];
            F4 w; w.v = *(const float4*)&W4[k * 128 + j0];
            #pragma unroll
            for (int jj = 0; jj < 4; ++jj)
                #pragma unroll
                for (int pp = 0; pp < 4; ++pp)
                    acc[jj][pp] = fmaf(a.f[pp], w.f[jj], acc[jj][pp]);
        }
        #pragma unroll
        for (int jj = 0; jj < 4; ++jj) {
            F4 v;
            #pragma unroll
            for (int pp = 0; pp < 4; ++pp) v.f[pp] = fmaxf(acc[jj][pp], 0.f);
            *(float4*)&h5T[j0 + jj][p0] = v.v;
        }
    }
    __syncthreads();

    // ---- head: 128 -> 13 ----
    {
        #pragma unroll
        for (int pass = 0; pass < 2; ++pass) {
            int p = (t >> 4) + pass * 16;
            int j = t & 15;
            if (j < 13 && base + p < NSEG) {
                float acc = bh[j];
                #pragma unroll 4
                for (int k = 0; k < 128; ++k)
                    acc = fmaf(h5T[k][p], Wh[k * 13 + j], acc);
                out[(base + p) * 13 + j] = acc;
            }
        }
    }
}

extern "C" void kernel_launch(void* const* d_in, const int* in_sizes, int n_in,
                              void* d_out, int out_size, void* d_ws, size_t ws_size,
                              hipStream_t stream)
{
    const float* x  = (const float*)d_in[0];
    const int*   idx= (const int*)  d_in[1];
    const float* W0 = (const float*)d_in[2];
    const float* b0 = (const float*)d_in[3];
    const float* W1 = (const float*)d_in[4];
    const float* b1 = (const float*)d_in[5];
    const float* W2 = (const float*)d_in[6];
    const float* b2 = (const float*)d_in[7];
    const float* W3 = (const float*)d_in[8];
    const float* b3 = (const float*)d_in[9];
    const float* W4 = (const float*)d_in[10];
    const float* b4 = (const float*)d_in[11];
    const float* Wh = (const float*)d_in[12];
    const float* bh = (const float*)d_in[13];
    float* out = (float*)d_out;

    // ws layout (u32 units): counts[50048] | start[50048] | perm[1000000] | g[12.8M]
    // counts region is dead after scan -> reused for the packed weights (81920 B).
    unsigned* counts = (unsigned*)d_ws;
    unsigned* start  = counts + 50048;
    unsigned* perm   = start + 50048;
    float*    g      = (float*)(perm + 1000000);
    unsigned short* wp = (unsigned short*)counts;   // packed W1|W2 (bf16)

    hipMemsetAsync(counts, 0, NSEG * sizeof(unsigned), stream);
    hist_kernel   <<<1024, 256, 0, stream>>>(idx, counts);
    scan_kernel   <<<1, 1024, 0, stream>>>(counts, start);
    pack_weights  <<<160, 256, 0, stream>>>(W1, W2, wp);          // counts now dead
    scatter_kernel<<<1024, 256, 0, stream>>>(idx, start, perm);   // start[s] -> end-of-s
    phase1m       <<<NSEG / SPB, 256, 0, stream>>>(x, idx, start, perm,
                                                   W0, b0, wp, b1, b2, g);
    phase2        <<<(NSEG + P2 - 1) / P2, 256, 0, stream>>>(g, W3, b3, W4, b4, Wh, bh, out);
}

// Round 7
// 610.606 us; speedup vs baseline: 9.0937x; 1.4450x over previous
//
#include <hip/hip_runtime.h>
#include <hip/hip_bf16.h>

#define NPTS 1000000
#define NSEG 50000
#define SPB  8       // segments per block (phase 1)
#define LDP  36      // padded LDS row stride (phase-1 xsT / fp32 fallback)

typedef __attribute__((ext_vector_type(8))) short bf16x8;   // 8 bf16 = 4 VGPR (MFMA A/B)
typedef __attribute__((ext_vector_type(4))) float f32x4;    // MFMA C/D

union F4 { float4 v; float f[4]; };

__device__ __forceinline__ unsigned short f2bf(float f) {
    union { __hip_bfloat16 h; unsigned short u; } cv;
    cv.h = __float2bfloat16(f);
    return cv.u;
}
__device__ __forceinline__ float bf2f(unsigned short u) {
    union { unsigned short u; __hip_bfloat16 h; } cv;
    cv.u = u;
    return __bfloat162float(cv.h);
}

#define MFMA16(a, b, c) __builtin_amdgcn_mfma_f32_16x16x32_bf16(a, b, c, 0, 0, 0)

// ---------- sort machinery ----------
__global__ __launch_bounds__(256) void hist_kernel(const int* __restrict__ idx,
                                                   unsigned* __restrict__ counts) {
    int i = blockIdx.x * blockDim.x + threadIdx.x;
    for (; i < NPTS; i += gridDim.x * blockDim.x) atomicAdd(&counts[idx[i]], 1u);
}

// parallel scan, 3 stages
__global__ __launch_bounds__(1024) void scan1_kernel(const unsigned* __restrict__ counts,
                                                     unsigned* __restrict__ start,
                                                     unsigned* __restrict__ bsum) {
    __shared__ unsigned tmp[1024];
    const int t = threadIdx.x;
    const int i = blockIdx.x * 1024 + t;
    unsigned v = (i < NSEG) ? counts[i] : 0u;
    tmp[t] = v;
    __syncthreads();
    for (int off = 1; off < 1024; off <<= 1) {
        unsigned add = (t >= off) ? tmp[t - off] : 0u;
        __syncthreads();
        tmp[t] += add;
        __syncthreads();
    }
    if (i < NSEG) start[i] = tmp[t] - v;        // block-local exclusive
    if (t == 1023) bsum[blockIdx.x] = tmp[1023];
}

__global__ __launch_bounds__(64) void scan2_kernel(unsigned* __restrict__ bsum,
                                                   unsigned* __restrict__ boff,
                                                   int nblk) {
    const int t = threadIdx.x;
    unsigned v = (t < nblk) ? bsum[t] : 0u;
    unsigned own = v;
    for (int off = 1; off < 64; off <<= 1) {
        unsigned u = __shfl_up(v, off, 64);
        if (t >= off) v += u;
    }
    if (t < nblk) boff[t] = v - own;            // exclusive
}

__global__ __launch_bounds__(1024) void scan3_kernel(unsigned* __restrict__ start,
                                                     const unsigned* __restrict__ boff) {
    const int i = blockIdx.x * 1024 + threadIdx.x;
    if (i < NSEG) start[i] += boff[blockIdx.x];
}

__global__ __launch_bounds__(256) void scatter_kernel(const int* __restrict__ idx,
                                                      unsigned* __restrict__ start,
                                                      unsigned* __restrict__ perm) {
    int i = blockIdx.x * blockDim.x + threadIdx.x;
    for (; i < NPTS; i += gridDim.x * blockDim.x) {
        int s = idx[i];
        unsigned pos = atomicAdd(&start[s], 1u);
        perm[pos] = (unsigned)i;
    }
}

// ---------- weight packing into MFMA B-fragment order (bf16) ----------
// wp   (ushort): W1 [0,8192) {8nt,2kt}, W2 [8192,40960) {16nt,4kt}, Wh [40960,43008) {1nt,4kt}
// wp34 (ushort): W3 [0,65536) {16nt,8kt}, W4 [65536,98304) {8nt,8kt}
// B-frag (16x16x32): lane l holds B[k = kt*32 + (l>>4)*8 + e][n = nt*16 + (l&15)]
__global__ __launch_bounds__(256) void pack_weights(const float* __restrict__ W1,
                                                    const float* __restrict__ W2,
                                                    const float* __restrict__ Wh,
                                                    const float* __restrict__ W3,
                                                    const float* __restrict__ W4,
                                                    unsigned short* __restrict__ wp,
                                                    unsigned short* __restrict__ wp34,
                                                    int total) {
    int i = blockIdx.x * 256 + threadIdx.x;
    for (; i < total; i += gridDim.x * 256) {
        if (i < 43008) {
            if (i < 8192) {
                int e = i & 7, l = (i >> 3) & 63, kt = (i >> 9) & 1, nt = i >> 10;
                int k = kt * 32 + (l >> 4) * 8 + e, n = nt * 16 + (l & 15);
                wp[i] = f2bf(W1[k * 128 + n]);
            } else if (i < 40960) {
                int j = i - 8192;
                int e = j & 7, l = (j >> 3) & 63, kt = (j >> 9) & 3, nt = j >> 11;
                int k = kt * 32 + (l >> 4) * 8 + e, n = nt * 16 + (l & 15);
                wp[i] = f2bf(W2[k * 256 + n]);
            } else {
                int j = i - 40960;
                int e = j & 7, l = (j >> 3) & 63, kt = j >> 9;
                int k = kt * 32 + (l >> 4) * 8 + e, n = l & 15;
                wp[i] = (n < 13) ? f2bf(Wh[k * 13 + n]) : 0;
            }
        } else {
            int i2 = i - 43008;
            if (i2 < 65536) {
                int e = i2 & 7, l = (i2 >> 3) & 63, kt = (i2 >> 9) & 7, nt = i2 >> 12;
                int k = kt * 32 + (l >> 4) * 8 + e, n = nt * 16 + (l & 15);
                wp34[i2] = f2bf(W3[k * 256 + n]);
            } else {
                int j = i2 - 65536;
                int e = j & 7, l = (j >> 3) & 63, kt = (j >> 9) & 7, nt = j >> 12;
                int k = kt * 32 + (l >> 4) * 8 + e, n = nt * 16 + (l & 15);
                wp34[i2] = f2bf(W4[k * 128 + n]);
            }
        }
    }
}

// ---------- Phase 1: point MLP (MFMA L1/L2, hi/lo split) + segment max ----------
__global__ __launch_bounds__(256) void phase1m(
    const float* __restrict__ x, const int* __restrict__ idx,
    const unsigned* __restrict__ endofs, const unsigned* __restrict__ perm,
    const float* __restrict__ W0, const float* __restrict__ b0,
    const unsigned short* __restrict__ wp,
    const float* __restrict__ b1, const float* __restrict__ b2,
    float* __restrict__ g)
{
    __shared__ __align__(16) unsigned short h1hi[32 * 72];
    __shared__ __align__(16) unsigned short h1lo[32 * 72];
    __shared__ __align__(16) unsigned short h2hi[32 * 136];
    __shared__ __align__(16) unsigned short h2lo[32 * 136];
    __shared__ float xsT[11][LDP];
    __shared__ float w0s[11 * 64];
    __shared__ unsigned gmax[SPB][264];
    __shared__ int segl[32];

    const int t    = threadIdx.x;
    const int lane = t & 63;
    const int w    = t >> 6;
    const int col  = lane & 15;
    const int grp  = lane >> 4;
    const int s0   = blockIdx.x * SPB;

    const unsigned A = (s0 == 0) ? 0u : endofs[s0 - 1];
    const unsigned B = endofs[s0 + SPB - 1];

    const int nt2 = w * 2;
    const int nt4 = w * 4;

    bf16x8 w1f[2][2], w2f[4][4];
    #pragma unroll
    for (int n = 0; n < 2; ++n)
        #pragma unroll
        for (int kt = 0; kt < 2; ++kt)
            w1f[n][kt] = *(const bf16x8*)&wp[(((nt2 + n) * 2 + kt) * 64 + lane) * 8];
    #pragma unroll
    for (int n = 0; n < 4; ++n)
        #pragma unroll
        for (int kt = 0; kt < 4; ++kt)
            w2f[n][kt] = *(const bf16x8*)&wp[8192 + (((nt4 + n) * 4 + kt) * 64 + lane) * 8];
    float bias1[2], bias2[4];
    #pragma unroll
    for (int n = 0; n < 2; ++n) bias1[n] = b1[(nt2 + n) * 16 + col];
    #pragma unroll
    for (int n = 0; n < 4; ++n) bias2[n] = b2[(nt4 + n) * 16 + col];

    const int p0 = (t & 7) << 2;
    const int j0 = (t >> 3) << 1;
    float bias0a = b0[j0], bias0b = b0[j0 + 1];

    for (int i = t; i < SPB * 264; i += 256) ((unsigned*)gmax)[i] = 0u;
    for (int i = t; i < 11 * 64; i += 256) w0s[i] = W0[i];
    __syncthreads();

    const int nchunk = (int)(B - A + 31u) >> 5;
    for (int c = 0; c < nchunk; ++c) {
        if (t < 32) {
            unsigned gp = A + ((unsigned)c << 5) + (unsigned)t;
            segl[t] = (gp < B) ? (idx[perm[gp]] - s0) : -1;
        }
        for (int i = t; i < 32 * 11; i += 256) {
            int p = i / 11, ch = i - p * 11;
            unsigned gp = A + ((unsigned)c << 5) + (unsigned)p;
            float v = 0.f;
            if (gp < B) v = x[perm[gp] * 11 + ch];
            xsT[ch][p] = v;
        }
        __syncthreads();

        // L0: 11 -> 64 fp32
        {
            float acc0[2][4];
            #pragma unroll
            for (int pp = 0; pp < 4; ++pp) { acc0[0][pp] = bias0a; acc0[1][pp] = bias0b; }
            #pragma unroll
            for (int k = 0; k < 11; ++k) {
                F4 a; a.v = *(const float4*)&xsT[k][p0];
                float wv0 = w0s[k * 64 + j0];
                float wv1 = w0s[k * 64 + j0 + 1];
                #pragma unroll
                for (int pp = 0; pp < 4; ++pp) {
                    acc0[0][pp] = fmaf(a.f[pp], wv0, acc0[0][pp]);
                    acc0[1][pp] = fmaf(a.f[pp], wv1, acc0[1][pp]);
                }
            }
            #pragma unroll
            for (int pp = 0; pp < 4; ++pp) {
                int pt = p0 + pp;
                float v0 = fmaxf(acc0[0][pp], 0.f);
                float v1 = fmaxf(acc0[1][pp], 0.f);
                unsigned short h0 = f2bf(v0), h1v = f2bf(v1);
                unsigned short l0 = f2bf(v0 - bf2f(h0)), l1v = f2bf(v1 - bf2f(h1v));
                *(unsigned*)&h1hi[pt * 72 + j0] = (unsigned)h0 | ((unsigned)h1v << 16);
                *(unsigned*)&h1lo[pt * 72 + j0] = (unsigned)l0 | ((unsigned)l1v << 16);
            }
        }
        __syncthreads();

        // L1: 64 -> 128 MFMA
        {
            f32x4 acc[2][2];
            #pragma unroll
            for (int m = 0; m < 2; ++m)
                #pragma unroll
                for (int n = 0; n < 2; ++n) {
                    float b = bias1[n];
                    acc[m][n] = (f32x4){b, b, b, b};
                }
            #pragma unroll
            for (int kt = 0; kt < 2; ++kt) {
                bf16x8 ahi[2], alo[2];
                #pragma unroll
                for (int m = 0; m < 2; ++m) {
                    int off = (m * 16 + col) * 72 + kt * 32 + grp * 8;
                    ahi[m] = *(const bf16x8*)&h1hi[off];
                    alo[m] = *(const bf16x8*)&h1lo[off];
                }
                #pragma unroll
                for (int n = 0; n < 2; ++n)
                    #pragma unroll
                    for (int m = 0; m < 2; ++m) {
                        acc[m][n] = MFMA16(ahi[m], w1f[n][kt], acc[m][n]);
                        acc[m][n] = MFMA16(alo[m], w1f[n][kt], acc[m][n]);
                    }
            }
            #pragma unroll
            for (int m = 0; m < 2; ++m)
                #pragma unroll
                for (int n = 0; n < 2; ++n) {
                    int ch = (nt2 + n) * 16 + col;
                    #pragma unroll
                    for (int r = 0; r < 4; ++r) {
                        int pt = m * 16 + grp * 4 + r;
                        float v = fmaxf(acc[m][n][r], 0.f);
                        unsigned short hi = f2bf(v);
                        h2hi[pt * 136 + ch] = hi;
                        h2lo[pt * 136 + ch] = f2bf(v - bf2f(hi));
                    }
                }
        }
        __syncthreads();

        // L2: 128 -> 256 MFMA + relu + LDS segment max
        {
            f32x4 acc2[2][4];
            #pragma unroll
            for (int m = 0; m < 2; ++m)
                #pragma unroll
                for (int n = 0; n < 4; ++n) {
                    float b = bias2[n];
                    acc2[m][n] = (f32x4){b, b, b, b};
                }
            #pragma unroll
            for (int kt = 0; kt < 4; ++kt) {
                bf16x8 ahi[2], alo[2];
                #pragma unroll
                for (int m = 0; m < 2; ++m) {
                    int off = (m * 16 + col) * 136 + kt * 32 + grp * 8;
                    ahi[m] = *(const bf16x8*)&h2hi[off];
                    alo[m] = *(const bf16x8*)&h2lo[off];
                }
                #pragma unroll
                for (int n = 0; n < 4; ++n)
                    #pragma unroll
                    for (int m = 0; m < 2; ++m) {
                        acc2[m][n] = MFMA16(ahi[m], w2f[n][kt], acc2[m][n]);
                        acc2[m][n] = MFMA16(alo[m], w2f[n][kt], acc2[m][n]);
                    }
            }
            int slv[2][4];
            #pragma unroll
            for (int m = 0; m < 2; ++m)
                #pragma unroll
                for (int r = 0; r < 4; ++r)
                    slv[m][r] = segl[m * 16 + grp * 4 + r];
            #pragma unroll
            for (int m = 0; m < 2; ++m) {
                if (slv[m][0] < 0) continue;
                #pragma unroll
                for (int n = 0; n < 4; ++n) {
                    int ch = (nt4 + n) * 16 + col;
                    float v0 = fmaxf(acc2[m][n][0], 0.f);
                    float v1 = fmaxf(acc2[m][n][1], 0.f);
                    float v2 = fmaxf(acc2[m][n][2], 0.f);
                    float v3 = fmaxf(acc2[m][n][3], 0.f);
                    if (slv[m][0] == slv[m][3]) {
                        float mx = fmaxf(fmaxf(v0, v1), fmaxf(v2, v3));
                        atomicMax(&gmax[slv[m][0]][ch], __float_as_uint(mx));
                    } else {
                        atomicMax(&gmax[slv[m][0]][ch], __float_as_uint(v0));
                        if (slv[m][1] >= 0) atomicMax(&gmax[slv[m][1]][ch], __float_as_uint(v1));
                        if (slv[m][2] >= 0) atomicMax(&gmax[slv[m][2]][ch], __float_as_uint(v2));
                        if (slv[m][3] >= 0) atomicMax(&gmax[slv[m][3]][ch], __float_as_uint(v3));
                    }
                }
            }
        }
        __syncthreads();
    }

    for (int i = t; i < SPB * 256; i += 256) {
        int sl = i >> 8, ch = i & 255;
        g[(s0 + sl) * 256 + ch] = __uint_as_float(gmax[sl][ch]);
    }
}

// ---------- Phase 2 (MFMA): 16 segments/block, hi/lo split activations ----------
__global__ __launch_bounds__(256) void phase2m(
    const float* __restrict__ g,
    const unsigned short* __restrict__ wp,     // Wh frags at +40960
    const unsigned short* __restrict__ wp34,   // W3 [0,65536), W4 [65536,98304)
    const float* __restrict__ b3, const float* __restrict__ b4,
    const float* __restrict__ bh,
    float* __restrict__ out)
{
    __shared__ __align__(16) unsigned short gThi[16 * 264];
    __shared__ __align__(16) unsigned short gTlo[16 * 264];
    __shared__ __align__(16) unsigned short h4hi[16 * 264];
    __shared__ __align__(16) unsigned short h4lo[16 * 264];
    __shared__ __align__(16) unsigned short h5hi[16 * 136];
    __shared__ __align__(16) unsigned short h5lo[16 * 136];

    const int t    = threadIdx.x;
    const int lane = t & 63;
    const int w    = t >> 6;
    const int col  = lane & 15;
    const int grp  = lane >> 4;
    const int seg0 = blockIdx.x * 16;

    // stage g -> hi/lo bf16 planes, segment-major
    for (int i = t; i < 16 * 64; i += 256) {
        int s = i >> 6, c4 = (i & 63) << 2;
        F4 v; v.v = *(const float4*)&g[(seg0 + s) * 256 + c4];
        unsigned short h[4], l[4];
        #pragma unroll
        for (int e = 0; e < 4; ++e) {
            h[e] = f2bf(v.f[e]);
            l[e] = f2bf(v.f[e] - bf2f(h[e]));
        }
        *(unsigned*)&gThi[s * 264 + c4]     = (unsigned)h[0] | ((unsigned)h[1] << 16);
        *(unsigned*)&gThi[s * 264 + c4 + 2] = (unsigned)h[2] | ((unsigned)h[3] << 16);
        *(unsigned*)&gTlo[s * 264 + c4]     = (unsigned)l[0] | ((unsigned)l[1] << 16);
        *(unsigned*)&gTlo[s * 264 + c4 + 2] = (unsigned)l[2] | ((unsigned)l[3] << 16);
    }
    __syncthreads();

    // L3: 256 -> 256 (per wave: 4 n-tiles)
    {
        f32x4 acc[4];
        #pragma unroll
        for (int n = 0; n < 4; ++n) {
            float b = b3[(w * 4 + n) * 16 + col];
            acc[n] = (f32x4){b, b, b, b};
        }
        #pragma unroll
        for (int kt = 0; kt < 8; ++kt) {
            int aoff = col * 264 + kt * 32 + grp * 8;
            bf16x8 ahi = *(const bf16x8*)&gThi[aoff];
            bf16x8 alo = *(const bf16x8*)&gTlo[aoff];
            #pragma unroll
            for (int n = 0; n < 4; ++n) {
                bf16x8 bw = *(const bf16x8*)&wp34[(((w * 4 + n) * 8 + kt) * 64 + lane) * 8];
                acc[n] = MFMA16(ahi, bw, acc[n]);
                acc[n] = MFMA16(alo, bw, acc[n]);
            }
        }
        #pragma unroll
        for (int n = 0; n < 4; ++n) {
            int ch = (w * 4 + n) * 16 + col;
            #pragma unroll
            for (int r = 0; r < 4; ++r) {
                int pt = grp * 4 + r;
                float v = fmaxf(acc[n][r], 0.f);
                unsigned short hi = f2bf(v);
                h4hi[pt * 264 + ch] = hi;
                h4lo[pt * 264 + ch] = f2bf(v - bf2f(hi));
            }
        }
    }
    __syncthreads();

    // L4: 256 -> 128 (per wave: 2 n-tiles)
    {
        f32x4 acc[2];
        #pragma unroll
        for (int n = 0; n < 2; ++n) {
            float b = b4[(w * 2 + n) * 16 + col];
            acc[n] = (f32x4){b, b, b, b};
        }
        #pragma unroll
        for (int kt = 0; kt < 8; ++kt) {
            int aoff = col * 264 + kt * 32 + grp * 8;
            bf16x8 ahi = *(const bf16x8*)&h4hi[aoff];
            bf16x8 alo = *(const bf16x8*)&h4lo[aoff];
            #pragma unroll
            for (int n = 0; n < 2; ++n) {
                bf16x8 bw = *(const bf16x8*)&wp34[65536 + (((w * 2 + n) * 8 + kt) * 64 + lane) * 8];
                acc[n] = MFMA16(ahi, bw, acc[n]);
                acc[n] = MFMA16(alo, bw, acc[n]);
            }
        }
        #pragma unroll
        for (int n = 0; n < 2; ++n) {
            int ch = (w * 2 + n) * 16 + col;
            #pragma unroll
            for (int r = 0; r < 4; ++r) {
                int pt = grp * 4 + r;
                float v = fmaxf(acc[n][r], 0.f);
                unsigned short hi = f2bf(v);
                h5hi[pt * 136 + ch] = hi;
                h5lo[pt * 136 + ch] = f2bf(v - bf2f(hi));
            }
        }
    }
    __syncthreads();

    // head: 128 -> 13 via one zero-padded MFMA n-tile (wave 0 only)
    if (w == 0) {
        float b = (col < 13) ? bh[col] : 0.f;
        f32x4 acc = (f32x4){b, b, b, b};
        #pragma unroll
        for (int kt = 0; kt < 4; ++kt) {
            int aoff = col * 136 + kt * 32 + grp * 8;
            bf16x8 ahi = *(const bf16x8*)&h5hi[aoff];
            bf16x8 alo = *(const bf16x8*)&h5lo[aoff];
            bf16x8 bw = *(const bf16x8*)&wp[40960 + ((kt * 64 + lane) * 8)];
            acc = MFMA16(ahi, bw, acc);
            acc = MFMA16(alo, bw, acc);
        }
        if (col < 13) {
            #pragma unroll
            for (int r = 0; r < 4; ++r)
                out[(seg0 + grp * 4 + r) * 13 + col] = acc[r];
        }
    }
}

// ---------------- Phase 2 fallback (fp32), used only if ws too small ----------------
__global__ __launch_bounds__(256) void phase2(
    const float* __restrict__ g,
    const float* __restrict__ W3, const float* __restrict__ b3,
    const float* __restrict__ W4, const float* __restrict__ b4,
    const float* __restrict__ Wh, const float* __restrict__ bh,
    float* __restrict__ out)
{
    __shared__ float gT[256][LDP];
    __shared__ float h4T[256][LDP];

    const int t = threadIdx.x;
    const long base = (long)blockIdx.x * 32;

    for (int i = t; i < 32 * 256; i += 256) {
        int s = i >> 8, c = i & 255;
        float v = 0.f;
        if (base + s < NSEG) v = g[(base + s) * 256 + c];
        gT[c][s] = v;
    }
    __syncthreads();

    const int p0 = (t & 7) << 2;
    const int jg = t >> 3;

    {
        const int j0 = jg << 3;
        float acc[8][4];
        #pragma unroll
        for (int jj = 0; jj < 8; ++jj) {
            float b = b3[j0 + jj];
            #pragma unroll
            for (int pp = 0; pp < 4; ++pp) acc[jj][pp] = b;
        }
        #pragma unroll 4
        for (int k = 0; k < 256; ++k) {
            F4 a;  a.v  = *(const float4*)&gT[k][p0];
            F4 wa; wa.v = *(const float4*)&W3[k * 256 + j0];
            F4 wb; wb.v = *(const float4*)&W3[k * 256 + j0 + 4];
            #pragma unroll
            for (int jj = 0; jj < 4; ++jj)
                #pragma unroll
                for (int pp = 0; pp < 4; ++pp) {
                    acc[jj][pp]     = fmaf(a.f[pp], wa.f[jj], acc[jj][pp]);
                    acc[jj + 4][pp] = fmaf(a.f[pp], wb.f[jj], acc[jj + 4][pp]);
                }
        }
        __syncthreads();
        #pragma unroll
        for (int jj = 0; jj < 8; ++jj) {
            F4 v;
            #pragma unroll
            for (int pp = 0; pp < 4; ++pp) v.f[pp] = fmaxf(acc[jj][pp], 0.f);
            *(float4*)&h4T[j0 + jj][p0] = v.v;
        }
    }
    __syncthreads();

    float (*h5T)[LDP] = gT;
    {
        const int j0 = jg << 2;
        float acc[4][4];
        #pragma unroll
        for (int jj = 0; jj < 4; ++jj) {
            float b = b4[j0 + jj];
            #pragma unroll
            for (int pp = 0; pp < 4; ++pp) acc[jj][pp] = b;
        }
        #pragma unroll 4
        for (int k = 0; k < 256; ++k) {
            F4 a; a.v = *(const float4*)&h4T[k][p0];
            F4 w; w.v = *(const float4*)&W4[k * 128 + j0];
            #pragma unroll
            for (int jj = 0; jj < 4; ++jj)
                #pragma unroll
                for (int pp = 0; pp < 4; ++pp)
                    acc[jj][pp] = fmaf(a.f[pp], w.f[jj], acc[jj][pp]);
        }
        #pragma unroll
        for (int jj = 0; jj < 4; ++jj) {
            F4 v;
            #pragma unroll
            for (int pp = 0; pp < 4; ++pp) v.f[pp] = fmaxf(acc[jj][pp], 0.f);
            *(float4*)&h5T[j0 + jj][p0] = v.v;
        }
    }
    __syncthreads();

    {
        #pragma unroll
        for (int pass = 0; pass < 2; ++pass) {
            int p = (t >> 4) + pass * 16;
            int j = t & 15;
            if (j < 13 && base + p < NSEG) {
                float acc = bh[j];
                #pragma unroll 4
                for (int k = 0; k < 128; ++k)
                    acc = fmaf(h5T[k][p], Wh[k * 13 + j], acc);
                out[(base + p) * 13 + j] = acc;
            }
        }
    }
}

extern "C" void kernel_launch(void* const* d_in, const int* in_sizes, int n_in,
                              void* d_out, int out_size, void* d_ws, size_t ws_size,
                              hipStream_t stream)
{
    const float* x  = (const float*)d_in[0];
    const int*   idx= (const int*)  d_in[1];
    const float* W0 = (const float*)d_in[2];
    const float* b0 = (const float*)d_in[3];
    const float* W1 = (const float*)d_in[4];
    const float* b1 = (const float*)d_in[5];
    const float* W2 = (const float*)d_in[6];
    const float* b2 = (const float*)d_in[7];
    const float* W3 = (const float*)d_in[8];
    const float* b3 = (const float*)d_in[9];
    const float* W4 = (const float*)d_in[10];
    const float* b4 = (const float*)d_in[11];
    const float* Wh = (const float*)d_in[12];
    const float* bh = (const float*)d_in[13];
    float* out = (float*)d_out;

    // ws layout (u32): counts[50048] | start[50048] | perm[1000000] | g[12.8M] | wp34
    unsigned* counts = (unsigned*)d_ws;
    unsigned* start  = counts + 50048;
    unsigned* perm   = start + 50048;
    float*    g      = (float*)(perm + 1000000);
    unsigned short* wp   = (unsigned short*)counts;        // W1|W2|Wh frags (86KB, counts dead after scan1)
    unsigned short* wp34 = (unsigned short*)(g + (size_t)NSEG * 256);  // W3|W4 frags (192KB)
    unsigned* bsum = (unsigned*)g;                         // scan scratch (dead before phase1m)
    unsigned* boff = bsum + 64;

    const size_t need34 = ((size_t)(perm + 1000000) - (size_t)d_ws)
                        + (size_t)NSEG * 256 * 4 + 98304 * 2;
    const bool useMfmaP2 = (ws_size >= need34);
    const int nblk = (NSEG + 1023) / 1024;   // 49

    hipMemsetAsync(counts, 0, NSEG * sizeof(unsigned), stream);
    hist_kernel <<<1024, 256, 0, stream>>>(idx, counts);
    scan1_kernel<<<nblk, 1024, 0, stream>>>(counts, start, bsum);
    scan2_kernel<<<1, 64, 0, stream>>>(bsum, boff, nblk);
    scan3_kernel<<<nblk, 1024, 0, stream>>>(start, boff);
    pack_weights<<<160, 256, 0, stream>>>(W1, W2, Wh, W3, W4, wp, wp34,
                                          useMfmaP2 ? 141312 : 43008);
    scatter_kernel<<<1024, 256, 0, stream>>>(idx, start, perm);   // start[s] -> end-of-s
    phase1m<<<NSEG / SPB, 256, 0, stream>>>(x, idx, start, perm,
                                            W0, b0, wp, b1, b2, g);
    if (useMfmaP2) {
        phase2m<<<NSEG / 16, 256, 0, stream>>>(g, wp, wp34, b3, b4, bh, out);
    } else {
        phase2<<<(NSEG + 31) / 32, 256, 0, stream>>>(g, W3, b3, W4, b4, Wh, bh, out);
    }
}

// Round 10
// 508.754 us; speedup vs baseline: 10.9143x; 1.2002x over previous
//
#include <hip/hip_runtime.h>
#include <hip/hip_bf16.h>

#define NPTS 1000000
#define NSEG 50000
#define SPB  8       // segments per block (phase 1)
#define LDP  36      // padded LDS row stride

typedef __attribute__((ext_vector_type(8))) short bf16x8;   // 8 bf16 = 4 VGPR (MFMA A/B)
typedef __attribute__((ext_vector_type(4))) float f32x4;    // MFMA C/D

union F4 { float4 v; float f[4]; };

__device__ __forceinline__ unsigned short f2bf(float f) {
    union { __hip_bfloat16 h; unsigned short u; } cv;
    cv.h = __float2bfloat16(f);
    return cv.u;
}
__device__ __forceinline__ float bf2f(unsigned short u) {
    union { unsigned short u; __hip_bfloat16 h; } cv;
    cv.u = u;
    return __bfloat162float(cv.h);
}

#define MFMA16(a, b, c) __builtin_amdgcn_mfma_f32_16x16x32_bf16(a, b, c, 0, 0, 0)

// ---------- sort machinery ----------
__global__ __launch_bounds__(256) void hist_kernel(const int* __restrict__ idx,
                                                   unsigned* __restrict__ counts) {
    int i = blockIdx.x * blockDim.x + threadIdx.x;
    for (; i < NPTS; i += gridDim.x * blockDim.x) atomicAdd(&counts[idx[i]], 1u);
}

__global__ __launch_bounds__(1024) void scan1_kernel(const unsigned* __restrict__ counts,
                                                     unsigned* __restrict__ start,
                                                     unsigned* __restrict__ bsum) {
    __shared__ unsigned tmp[1024];
    const int t = threadIdx.x;
    const int i = blockIdx.x * 1024 + t;
    unsigned v = (i < NSEG) ? counts[i] : 0u;
    tmp[t] = v;
    __syncthreads();
    for (int off = 1; off < 1024; off <<= 1) {
        unsigned add = (t >= off) ? tmp[t - off] : 0u;
        __syncthreads();
        tmp[t] += add;
        __syncthreads();
    }
    if (i < NSEG) start[i] = tmp[t] - v;
    if (t == 1023) bsum[blockIdx.x] = tmp[1023];
}

__global__ __launch_bounds__(64) void scan2_kernel(unsigned* __restrict__ bsum,
                                                   unsigned* __restrict__ boff,
                                                   int nblk) {
    const int t = threadIdx.x;
    unsigned v = (t < nblk) ? bsum[t] : 0u;
    unsigned own = v;
    for (int off = 1; off < 64; off <<= 1) {
        unsigned u = __shfl_up(v, off, 64);
        if (t >= off) v += u;
    }
    if (t < nblk) boff[t] = v - own;
}

__global__ __launch_bounds__(1024) void scan3_kernel(unsigned* __restrict__ start,
                                                     const unsigned* __restrict__ boff) {
    const int i = blockIdx.x * 1024 + threadIdx.x;
    if (i < NSEG) start[i] += boff[blockIdx.x];
}

// scatter x rows themselves into segment-sorted order (12-float padded rows).
// After this, start[s] == end offset of segment s.
__global__ __launch_bounds__(256) void scatter_x(const float* __restrict__ x,
                                                 const int* __restrict__ idx,
                                                 unsigned* __restrict__ start,
                                                 float* __restrict__ xs12) {
    int i = blockIdx.x * blockDim.x + threadIdx.x;
    for (; i < NPTS; i += gridDim.x * blockDim.x) {
        int s = idx[i];
        unsigned pos = atomicAdd(&start[s], 1u);
        const float* src = x + (size_t)i * 11;
        float* dst = xs12 + (size_t)pos * 12;
        #pragma unroll
        for (int c = 0; c < 11; ++c) dst[c] = src[c];
    }
}

// fallback: scatter point ids only
__global__ __launch_bounds__(256) void scatter_kernel(const int* __restrict__ idx,
                                                      unsigned* __restrict__ start,
                                                      unsigned* __restrict__ perm) {
    int i = blockIdx.x * blockDim.x + threadIdx.x;
    for (; i < NPTS; i += gridDim.x * blockDim.x) {
        int s = idx[i];
        unsigned pos = atomicAdd(&start[s], 1u);
        perm[pos] = (unsigned)i;
    }
}

// ---------- weight packing into MFMA B-fragment order (bf16) ----------
// wp   (ushort): W1 [0,8192) {8nt,2kt}, W2 [8192,40960) {16nt,4kt}, Wh [40960,43008) {1nt,4kt}
// wp34 (ushort): W3 [0,65536) {16nt,8kt}, W4 [65536,98304) {8nt,8kt}
// B-frag (16x16x32): lane l holds B[k = kt*32 + (l>>4)*8 + e][n = nt*16 + (l&15)]
__global__ __launch_bounds__(256) void pack_weights(const float* __restrict__ W1,
                                                    const float* __restrict__ W2,
                                                    const float* __restrict__ Wh,
                                                    const float* __restrict__ W3,
                                                    const float* __restrict__ W4,
                                                    unsigned short* __restrict__ wp,
                                                    unsigned short* __restrict__ wp34,
                                                    int total) {
    int i = blockIdx.x * 256 + threadIdx.x;
    for (; i < total; i += gridDim.x * 256) {
        if (i < 43008) {
            if (i < 8192) {
                int e = i & 7, l = (i >> 3) & 63, kt = (i >> 9) & 1, nt = i >> 10;
                int k = kt * 32 + (l >> 4) * 8 + e, n = nt * 16 + (l & 15);
                wp[i] = f2bf(W1[k * 128 + n]);
            } else if (i < 40960) {
                int j = i - 8192;
                int e = j & 7, l = (j >> 3) & 63, kt = (j >> 9) & 3, nt = j >> 11;
                int k = kt * 32 + (l >> 4) * 8 + e, n = nt * 16 + (l & 15);
                wp[i] = f2bf(W2[k * 256 + n]);
            } else {
                int j = i - 40960;
                int e = j & 7, l = (j >> 3) & 63, kt = j >> 9;
                int k = kt * 32 + (l >> 4) * 8 + e, n = l & 15;
                wp[i] = (n < 13) ? f2bf(Wh[k * 13 + n]) : 0;
            }
        } else {
            int i2 = i - 43008;
            if (i2 < 65536) {
                int e = i2 & 7, l = (i2 >> 3) & 63, kt = (i2 >> 9) & 7, nt = i2 >> 12;
                int k = kt * 32 + (l >> 4) * 8 + e, n = nt * 16 + (l & 15);
                wp34[i2] = f2bf(W3[k * 256 + n]);
            } else {
                int j = i2 - 65536;
                int e = j & 7, l = (j >> 3) & 63, kt = (j >> 9) & 7, nt = j >> 12;
                int k = kt * 32 + (l >> 4) * 8 + e, n = nt * 16 + (l & 15);
                wp34[i2] = f2bf(W4[k * 128 + n]);
            }
        }
    }
}

// ---------- Phase 1: point MLP (MFMA L1/L2, hi/lo split) + segment max ----------
// SX=true:  xsrc = xs12 (sorted, padded 12-float rows), coalesced staged, reg-prefetched
// SX=false: xsrc = x, gathered via perm (fallback)
// segl derived from segment boundaries (uniform compares) — no dependent idx load.
template<bool SX>
__global__ __launch_bounds__(256) void phase1m2(
    const float* __restrict__ xsrc, const unsigned* __restrict__ perm,
    const unsigned* __restrict__ endofs,
    const float* __restrict__ W0, const float* __restrict__ b0,
    const unsigned short* __restrict__ wp,
    const float* __restrict__ b1, const float* __restrict__ b2,
    float* __restrict__ g)
{
    __shared__ __align__(16) unsigned short h1hi[32 * 72];
    __shared__ __align__(16) unsigned short h1lo[32 * 72];
    __shared__ __align__(16) unsigned short h2hi[32 * 136];
    __shared__ __align__(16) unsigned short h2lo[32 * 136];
    __shared__ float xsT[12][LDP];
    __shared__ float w0s[11 * 64];
    __shared__ unsigned gmax[SPB][264];
    __shared__ int segl[32];

    const int t    = threadIdx.x;
    const int lane = t & 63;
    const int w    = t >> 6;
    const int col  = lane & 15;
    const int grp  = lane >> 4;
    const int s0   = blockIdx.x * SPB;

    const unsigned A = (s0 == 0) ? 0u : endofs[s0 - 1];
    // segment end boundaries (uniform -> scalar regs)
    unsigned bnd[SPB];
    #pragma unroll
    for (int s = 0; s < SPB; ++s) bnd[s] = endofs[s0 + s];
    const unsigned B = bnd[SPB - 1];

    const int nt2 = w * 2;
    const int nt4 = w * 4;

    bf16x8 w1f[2][2], w2f[4][4];
    #pragma unroll
    for (int n = 0; n < 2; ++n)
        #pragma unroll
        for (int kt = 0; kt < 2; ++kt)
            w1f[n][kt] = *(const bf16x8*)&wp[(((nt2 + n) * 2 + kt) * 64 + lane) * 8];
    #pragma unroll
    for (int n = 0; n < 4; ++n)
        #pragma unroll
        for (int kt = 0; kt < 4; ++kt)
            w2f[n][kt] = *(const bf16x8*)&wp[8192 + (((nt4 + n) * 4 + kt) * 64 + lane) * 8];
    float bias1[2], bias2[4];
    #pragma unroll
    for (int n = 0; n < 2; ++n) bias1[n] = b1[(nt2 + n) * 16 + col];
    #pragma unroll
    for (int n = 0; n < 4; ++n) bias2[n] = b2[(nt4 + n) * 16 + col];

    const int p0 = (t & 7) << 2;
    const int j0 = (t >> 3) << 1;
    float bias0a = b0[j0], bias0b = b0[j0 + 1];

    for (int i = t; i < SPB * 264; i += 256) ((unsigned*)gmax)[i] = 0u;
    for (int i = t; i < 11 * 64; i += 256) w0s[i] = W0[i];
    __syncthreads();

    const int nchunk = (int)(B - A + 31u) >> 5;

    // prefetch chunk 0 (sorted path): 96 float4 = 32 points x 12 floats
    const float4* xs4 = (const float4*)xsrc;
    float4 xreg = make_float4(0.f, 0.f, 0.f, 0.f);
    if (SX && nchunk > 0 && t < 96) xreg = xs4[(size_t)A * 3 + t];

    for (int c = 0; c < nchunk; ++c) {
        // ---- stage ----
        if constexpr (SX) {
            if (t < 96) {
                int p = t / 3, j = t - p * 3;
                xsT[4 * j + 0][p] = xreg.x;
                xsT[4 * j + 1][p] = xreg.y;
                xsT[4 * j + 2][p] = xreg.z;
                xsT[4 * j + 3][p] = xreg.w;
            }
        } else {
            for (int i = t; i < 32 * 11; i += 256) {
                int p = i / 11, ch = i - p * 11;
                unsigned gp = A + ((unsigned)c << 5) + (unsigned)p;
                float v = 0.f;
                if (gp < B) v = xsrc[(size_t)perm[gp] * 11 + ch];
                xsT[ch][p] = v;
            }
        }
        if (t < 32) {
            unsigned gp = A + ((unsigned)c << 5) + (unsigned)t;
            int sl = -1;
            if (gp < B) {
                sl = 0;
                #pragma unroll
                for (int s = 0; s < SPB - 1; ++s) sl += (gp >= bnd[s]) ? 1 : 0;
            }
            segl[t] = sl;
        }
        __syncthreads();

        // issue next chunk's loads now; consumed at next iteration's stage-write
        if (SX && (c + 1 < nchunk) && t < 96)
            xreg = xs4[((size_t)A + ((size_t)(c + 1) << 5)) * 3 + t];

        // ---- L0: 11 -> 64 fp32 ----
        {
            float acc0[2][4];
            #pragma unroll
            for (int pp = 0; pp < 4; ++pp) { acc0[0][pp] = bias0a; acc0[1][pp] = bias0b; }
            #pragma unroll
            for (int k = 0; k < 11; ++k) {
                F4 a; a.v = *(const float4*)&xsT[k][p0];
                float wv0 = w0s[k * 64 + j0];
                float wv1 = w0s[k * 64 + j0 + 1];
                #pragma unroll
                for (int pp = 0; pp < 4; ++pp) {
                    acc0[0][pp] = fmaf(a.f[pp], wv0, acc0[0][pp]);
                    acc0[1][pp] = fmaf(a.f[pp], wv1, acc0[1][pp]);
                }
            }
            #pragma unroll
            for (int pp = 0; pp < 4; ++pp) {
                int pt = p0 + pp;
                float v0 = fmaxf(acc0[0][pp], 0.f);
                float v1 = fmaxf(acc0[1][pp], 0.f);
                unsigned short h0 = f2bf(v0), h1v = f2bf(v1);
                unsigned short l0 = f2bf(v0 - bf2f(h0)), l1v = f2bf(v1 - bf2f(h1v));
                *(unsigned*)&h1hi[pt * 72 + j0] = (unsigned)h0 | ((unsigned)h1v << 16);
                *(unsigned*)&h1lo[pt * 72 + j0] = (unsigned)l0 | ((unsigned)l1v << 16);
            }
        }
        __syncthreads();

        // ---- L1: 64 -> 128 MFMA ----
        {
            f32x4 acc[2][2];
            #pragma unroll
            for (int m = 0; m < 2; ++m)
                #pragma unroll
                for (int n = 0; n < 2; ++n) {
                    float b = bias1[n];
                    acc[m][n] = (f32x4){b, b, b, b};
                }
            #pragma unroll
            for (int kt = 0; kt < 2; ++kt) {
                bf16x8 ahi[2], alo[2];
                #pragma unroll
                for (int m = 0; m < 2; ++m) {
                    int off = (m * 16 + col) * 72 + kt * 32 + grp * 8;
                    ahi[m] = *(const bf16x8*)&h1hi[off];
                    alo[m] = *(const bf16x8*)&h1lo[off];
                }
                #pragma unroll
                for (int n = 0; n < 2; ++n)
                    #pragma unroll
                    for (int m = 0; m < 2; ++m) {
                        acc[m][n] = MFMA16(ahi[m], w1f[n][kt], acc[m][n]);
                        acc[m][n] = MFMA16(alo[m], w1f[n][kt], acc[m][n]);
                    }
            }
            #pragma unroll
            for (int m = 0; m < 2; ++m)
                #pragma unroll
                for (int n = 0; n < 2; ++n) {
                    int ch = (nt2 + n) * 16 + col;
                    #pragma unroll
                    for (int r = 0; r < 4; ++r) {
                        int pt = m * 16 + grp * 4 + r;
                        float v = fmaxf(acc[m][n][r], 0.f);
                        unsigned short hi = f2bf(v);
                        h2hi[pt * 136 + ch] = hi;
                        h2lo[pt * 136 + ch] = f2bf(v - bf2f(hi));
                    }
                }
        }
        __syncthreads();

        // ---- L2: 128 -> 256 MFMA + relu + LDS segment max ----
        {
            f32x4 acc2[2][4];
            #pragma unroll
            for (int m = 0; m < 2; ++m)
                #pragma unroll
                for (int n = 0; n < 4; ++n) {
                    float b = bias2[n];
                    acc2[m][n] = (f32x4){b, b, b, b};
                }
            #pragma unroll
            for (int kt = 0; kt < 4; ++kt) {
                bf16x8 ahi[2], alo[2];
                #pragma unroll
                for (int m = 0; m < 2; ++m) {
                    int off = (m * 16 + col) * 136 + kt * 32 + grp * 8;
                    ahi[m] = *(const bf16x8*)&h2hi[off];
                    alo[m] = *(const bf16x8*)&h2lo[off];
                }
                #pragma unroll
                for (int n = 0; n < 4; ++n)
                    #pragma unroll
                    for (int m = 0; m < 2; ++m) {
                        acc2[m][n] = MFMA16(ahi[m], w2f[n][kt], acc2[m][n]);
                        acc2[m][n] = MFMA16(alo[m], w2f[n][kt], acc2[m][n]);
                    }
            }
            int slv[2][4];
            #pragma unroll
            for (int m = 0; m < 2; ++m)
                #pragma unroll
                for (int r = 0; r < 4; ++r)
                    slv[m][r] = segl[m * 16 + grp * 4 + r];
            #pragma unroll
            for (int m = 0; m < 2; ++m) {
                if (slv[m][0] < 0) continue;
                #pragma unroll
                for (int n = 0; n < 4; ++n) {
                    int ch = (nt4 + n) * 16 + col;
                    float v0 = fmaxf(acc2[m][n][0], 0.f);
                    float v1 = fmaxf(acc2[m][n][1], 0.f);
                    float v2 = fmaxf(acc2[m][n][2], 0.f);
                    float v3 = fmaxf(acc2[m][n][3], 0.f);
                    if (slv[m][0] == slv[m][3]) {
                        float mx = fmaxf(fmaxf(v0, v1), fmaxf(v2, v3));
                        atomicMax(&gmax[slv[m][0]][ch], __float_as_uint(mx));
                    } else {
                        atomicMax(&gmax[slv[m][0]][ch], __float_as_uint(v0));
                        if (slv[m][1] >= 0) atomicMax(&gmax[slv[m][1]][ch], __float_as_uint(v1));
                        if (slv[m][2] >= 0) atomicMax(&gmax[slv[m][2]][ch], __float_as_uint(v2));
                        if (slv[m][3] >= 0) atomicMax(&gmax[slv[m][3]][ch], __float_as_uint(v3));
                    }
                }
            }
        }
        __syncthreads();
    }

    for (int i = t; i < SPB * 256; i += 256) {
        int sl = i >> 8, ch = i & 255;
        g[(size_t)(s0 + sl) * 256 + ch] = __uint_as_float(gmax[sl][ch]);
    }
}

// ---------- Phase 2 (MFMA): 16 segments/block, hi/lo split activations ----------
__global__ __launch_bounds__(256) void phase2m(
    const float* __restrict__ g,
    const unsigned short* __restrict__ wp,     // Wh frags at +40960
    const unsigned short* __restrict__ wp34,   // W3 [0,65536), W4 [65536,98304)
    const float* __restrict__ b3, const float* __restrict__ b4,
    const float* __restrict__ bh,
    float* __restrict__ out)
{
    __shared__ __align__(16) unsigned short gThi[16 * 264];
    __shared__ __align__(16) unsigned short gTlo[16 * 264];
    __shared__ __align__(16) unsigned short h4hi[16 * 264];
    __shared__ __align__(16) unsigned short h4lo[16 * 264];
    __shared__ __align__(16) unsigned short h5hi[16 * 136];
    __shared__ __align__(16) unsigned short h5lo[16 * 136];

    const int t    = threadIdx.x;
    const int lane = t & 63;
    const int w    = t >> 6;
    const int col  = lane & 15;
    const int grp  = lane >> 4;
    const int seg0 = blockIdx.x * 16;

    for (int i = t; i < 16 * 64; i += 256) {
        int s = i >> 6, c4 = (i & 63) << 2;
        F4 v; v.v = *(const float4*)&g[(size_t)(seg0 + s) * 256 + c4];
        unsigned short h[4], l[4];
        #pragma unroll
        for (int e = 0; e < 4; ++e) {
            h[e] = f2bf(v.f[e]);
            l[e] = f2bf(v.f[e] - bf2f(h[e]));
        }
        *(unsigned*)&gThi[s * 264 + c4]     = (unsigned)h[0] | ((unsigned)h[1] << 16);
        *(unsigned*)&gThi[s * 264 + c4 + 2] = (unsigned)h[2] | ((unsigned)h[3] << 16);
        *(unsigned*)&gTlo[s * 264 + c4]     = (unsigned)l[0] | ((unsigned)l[1] << 16);
        *(unsigned*)&gTlo[s * 264 + c4 + 2] = (unsigned)l[2] | ((unsigned)l[3] << 16);
    }
    __syncthreads();

    // L3: 256 -> 256
    {
        f32x4 acc[4];
        #pragma unroll
        for (int n = 0; n < 4; ++n) {
            float b = b3[(w * 4 + n) * 16 + col];
            acc[n] = (f32x4){b, b, b, b};
        }
        #pragma unroll
        for (int kt = 0; kt < 8; ++kt) {
            int aoff = col * 264 + kt * 32 + grp * 8;
            bf16x8 ahi = *(const bf16x8*)&gThi[aoff];
            bf16x8 alo = *(const bf16x8*)&gTlo[aoff];
            #pragma unroll
            for (int n = 0; n < 4; ++n) {
                bf16x8 bw = *(const bf16x8*)&wp34[(((w * 4 + n) * 8 + kt) * 64 + lane) * 8];
                acc[n] = MFMA16(ahi, bw, acc[n]);
                acc[n] = MFMA16(alo, bw, acc[n]);
            }
        }
        #pragma unroll
        for (int n = 0; n < 4; ++n) {
            int ch = (w * 4 + n) * 16 + col;
            #pragma unroll
            for (int r = 0; r < 4; ++r) {
                int pt = grp * 4 + r;
                float v = fmaxf(acc[n][r], 0.f);
                unsigned short hi = f2bf(v);
                h4hi[pt * 264 + ch] = hi;
                h4lo[pt * 264 + ch] = f2bf(v - bf2f(hi));
            }
        }
    }
    __syncthreads();

    // L4: 256 -> 128
    {
        f32x4 acc[2];
        #pragma unroll
        for (int n = 0; n < 2; ++n) {
            float b = b4[(w * 2 + n) * 16 + col];
            acc[n] = (f32x4){b, b, b, b};
        }
        #pragma unroll
        for (int kt = 0; kt < 8; ++kt) {
            int aoff = col * 264 + kt * 32 + grp * 8;
            bf16x8 ahi = *(const bf16x8*)&h4hi[aoff];
            bf16x8 alo = *(const bf16x8*)&h4lo[aoff];
            #pragma unroll
            for (int n = 0; n < 2; ++n) {
                bf16x8 bw = *(const bf16x8*)&wp34[65536 + (((w * 2 + n) * 8 + kt) * 64 + lane) * 8];
                acc[n] = MFMA16(ahi, bw, acc[n]);
                acc[n] = MFMA16(alo, bw, acc[n]);
            }
        }
        #pragma unroll
        for (int n = 0; n < 2; ++n) {
            int ch = (w * 2 + n) * 16 + col;
            #pragma unroll
            for (int r = 0; r < 4; ++r) {
                int pt = grp * 4 + r;
                float v = fmaxf(acc[n][r], 0.f);
                unsigned short hi = f2bf(v);
                h5hi[pt * 136 + ch] = hi;
                h5lo[pt * 136 + ch] = f2bf(v - bf2f(hi));
            }
        }
    }
    __syncthreads();

    // head: 128 -> 13 (wave 0)
    if (w == 0) {
        float b = (col < 13) ? bh[col] : 0.f;
        f32x4 acc = (f32x4){b, b, b, b};
        #pragma unroll
        for (int kt = 0; kt < 4; ++kt) {
            int aoff = col * 136 + kt * 32 + grp * 8;
            bf16x8 ahi = *(const bf16x8*)&h5hi[aoff];
            bf16x8 alo = *(const bf16x8*)&h5lo[aoff];
            bf16x8 bw = *(const bf16x8*)&wp[40960 + ((kt * 64 + lane) * 8)];
            acc = MFMA16(ahi, bw, acc);
            acc = MFMA16(alo, bw, acc);
        }
        if (col < 13) {
            #pragma unroll
            for (int r = 0; r < 4; ++r)
                out[(size_t)(seg0 + grp * 4 + r) * 13 + col] = acc[r];
        }
    }
}

// ---------------- Phase 2 fallback (fp32), used only if ws too small ----------------
__global__ __launch_bounds__(256) void phase2(
    const float* __restrict__ g,
    const float* __restrict__ W3, const float* __restrict__ b3,
    const float* __restrict__ W4, const float* __restrict__ b4,
    const float* __restrict__ Wh, const float* __restrict__ bh,
    float* __restrict__ out)
{
    __shared__ float gT[256][LDP];
    __shared__ float h4T[256][LDP];

    const int t = threadIdx.x;
    const long base = (long)blockIdx.x * 32;

    for (int i = t; i < 32 * 256; i += 256) {
        int s = i >> 8, c = i & 255;
        float v = 0.f;
        if (base + s < NSEG) v = g[(base + s) * 256 + c];
        gT[c][s] = v;
    }
    __syncthreads();

    const int p0 = (t & 7) << 2;
    const int jg = t >> 3;

    {
        const int j0 = jg << 3;
        float acc[8][4];
        #pragma unroll
        for (int jj = 0; jj < 8; ++jj) {
            float b = b3[j0 + jj];
            #pragma unroll
            for (int pp = 0; pp < 4; ++pp) acc[jj][pp] = b;
        }
        #pragma unroll 4
        for (int k = 0; k < 256; ++k) {
            F4 a;  a.v  = *(const float4*)&gT[k][p0];
            F4 wa; wa.v = *(const float4*)&W3[k * 256 + j0];
            F4 wb; wb.v = *(const float4*)&W3[k * 256 + j0 + 4];
            #pragma unroll
            for (int jj = 0; jj < 4; ++jj)
                #pragma unroll
                for (int pp = 0; pp < 4; ++pp) {
                    acc[jj][pp]     = fmaf(a.f[pp], wa.f[jj], acc[jj][pp]);
                    acc[jj + 4][pp] = fmaf(a.f[pp], wb.f[jj], acc[jj + 4][pp]);
                }
        }
        __syncthreads();
        #pragma unroll
        for (int jj = 0; jj < 8; ++jj) {
            F4 v;
            #pragma unroll
            for (int pp = 0; pp < 4; ++pp) v.f[pp] = fmaxf(acc[jj][pp], 0.f);
            *(float4*)&h4T[j0 + jj][p0] = v.v;
        }
    }
    __syncthreads();

    float (*h5T)[LDP] = gT;
    {
        const int j0 = jg << 2;
        float acc[4][4];
        #pragma unroll
        for (int jj = 0; jj < 4; ++jj) {
            float b = b4[j0 + jj];
            #pragma unroll
            for (int pp = 0; pp < 4; ++pp) acc[jj][pp] = b;
        }
        #pragma unroll 4
        for (int k = 0; k < 256; ++k) {
            F4 a; a.v = *(const float4*)&h4T[k][p0];
            F4 w; w.v = *(const float4*)&W4[k * 128 + j0];
            #pragma unroll
            for (int jj = 0; jj < 4; ++jj)
                #pragma unroll
                for (int pp = 0; pp < 4; ++pp)
                    acc[jj][pp] = fmaf(a.f[pp], w.f[jj], acc[jj][pp]);
        }
        #pragma unroll
        for (int jj = 0; jj < 4; ++jj) {
            F4 v;
            #pragma unroll
            for (int pp = 0; pp < 4; ++pp) v.f[pp] = fmaxf(acc[jj][pp], 0.f);
            *(float4*)&h5T[j0 + jj][p0] = v.v;
        }
    }
    __syncthreads();

    {
        #pragma unroll
        for (int pass = 0; pass < 2; ++pass) {
            int p = (t >> 4) + pass * 16;
            int j = t & 15;
            if (j < 13 && base + p < NSEG) {
                float acc = bh[j];
                #pragma unroll 4
                for (int k = 0; k < 128; ++k)
                    acc = fmaf(h5T[k][p], Wh[k * 13 + j], acc);
                out[(base + p) * 13 + j] = acc;
            }
        }
    }
}

extern "C" void kernel_launch(void* const* d_in, const int* in_sizes, int n_in,
                              void* d_out, int out_size, void* d_ws, size_t ws_size,
                              hipStream_t stream)
{
    const float* x  = (const float*)d_in[0];
    const int*   idx= (const int*)  d_in[1];
    const float* W0 = (const float*)d_in[2];
    const float* b0 = (const float*)d_in[3];
    const float* W1 = (const float*)d_in[4];
    const float* b1 = (const float*)d_in[5];
    const float* W2 = (const float*)d_in[6];
    const float* b2 = (const float*)d_in[7];
    const float* W3 = (const float*)d_in[8];
    const float* b3 = (const float*)d_in[9];
    const float* W4 = (const float*)d_in[10];
    const float* b4 = (const float*)d_in[11];
    const float* Wh = (const float*)d_in[12];
    const float* bh = (const float*)d_in[13];
    float* out = (float*)d_out;

    unsigned* counts = (unsigned*)d_ws;
    unsigned* start  = counts + 50048;
    unsigned short* wp = (unsigned short*)counts;   // reuses counts after scan1

    // preferred layout: counts|start|xs12[12M f32]|g[12.8M f32]|wp34[98304 u16]
    const size_t need_x = (50048ull + 50048 + 12000000 + 12800000) * 4 + 98304 * 2;
    // fallback layout: counts|start|perm[1M u32]|g|wp34
    const size_t need_p = (50048ull + 50048 + 1000000 + 12800000) * 4 + 98304 * 2;

    const bool fitX = (ws_size >= need_x);
    const int nblk = (NSEG + 1023) / 1024;   // 49

    hipMemsetAsync(counts, 0, NSEG * sizeof(unsigned), stream);
    hist_kernel <<<1024, 256, 0, stream>>>(idx, counts);

    if (fitX) {
        float*    xs12 = (float*)(start + 50048);
        float*    g    = xs12 + 12000000;
        unsigned short* wp34 = (unsigned short*)(g + (size_t)NSEG * 256);
        unsigned* bsum = (unsigned*)g;               // scratch, dead before phase1
        unsigned* boff = bsum + 64;

        scan1_kernel<<<nblk, 1024, 0, stream>>>(counts, start, bsum);
        scan2_kernel<<<1, 64, 0, stream>>>(bsum, boff, nblk);
        scan3_kernel<<<nblk, 1024, 0, stream>>>(start, boff);
        pack_weights<<<160, 256, 0, stream>>>(W1, W2, Wh, W3, W4, wp, wp34, 141312);
        scatter_x   <<<3907, 256, 0, stream>>>(x, idx, start, xs12);
        phase1m2<true><<<NSEG / SPB, 256, 0, stream>>>(xs12, nullptr, start,
                                                       W0, b0, wp, b1, b2, g);
        phase2m<<<NSEG / 16, 256, 0, stream>>>(g, wp, wp34, b3, b4, bh, out);
    } else {
        unsigned* perm = start + 50048;
        float*    g    = (float*)(perm + 1000000);
        unsigned short* wp34 = (unsigned short*)(g + (size_t)NSEG * 256);
        unsigned* bsum = (unsigned*)g;
        unsigned* boff = bsum + 64;
        const bool useMfmaP2 = (ws_size >= need_p);

        scan1_kernel<<<nblk, 1024, 0, stream>>>(counts, start, bsum);
        scan2_kernel<<<1, 64, 0, stream>>>(bsum, boff, nblk);
        scan3_kernel<<<nblk, 1024, 0, stream>>>(start, boff);
        pack_weights<<<160, 256, 0, stream>>>(W1, W2, Wh, W3, W4, wp, wp34,
                                              useMfmaP2 ? 141312 : 43008);
        scatter_kernel<<<1024, 256, 0, stream>>>(idx, start, perm);
        phase1m2<false><<<NSEG / SPB, 256, 0, stream>>>(x, perm, start,
                                                        W0, b0, wp, b1, b2, g);
        if (useMfmaP2) {
            phase2m<<<NSEG / 16, 256, 0, stream>>>(g, wp, wp34, b3, b4, bh, out);
        } else {
            phase2<<<(NSEG + 31) / 32, 256, 0, stream>>>(g, W3, b3, W4, b4, Wh, bh, out);
        }
    }
}